// Round 1
// baseline (1523.640 us; speedup 1.0000x reference)
//
#include <hip/hip_runtime.h>
#include <math.h>

#define T_  16
#define DB2_ 512
#define H_  512
#define Hh_ 256
#define U_  1024
#define MC_ 8
#define MT_ 4
#define L_  64
#define K_  64
#define M_  (T_*U_)   // 16384

__device__ __forceinline__ float sigmoidf_(float x) { return 1.f / (1.f + expf(-x)); }

// ---------------------------------------------------------------------------
// Kernel 1: masked mean pooling for col (MC=8) and tab (MT=4) -> x2, x1
// grid (U, T), 256 threads, 2 h per thread (float2)
// ---------------------------------------------------------------------------
__global__ __launch_bounds__(256) void meanpool_kernel(
    const float* __restrict__ feat,
    const int* __restrict__ col_idx, const int* __restrict__ col_mask,
    const int* __restrict__ tab_idx, const int* __restrict__ tab_mask,
    float* __restrict__ x1 /*tab*/, float* __restrict__ x2 /*col*/)
{
    const int u = blockIdx.x;
    const int t = blockIdx.y;
    const int tid = threadIdx.x;

    int ci[MC_], cm[MC_], ti[MT_], tm[MT_];
    float cc = 0.f, tc = 0.f;
#pragma unroll
    for (int m = 0; m < MC_; ++m) { ci[m] = col_idx[u*MC_+m]; cm[m] = col_mask[u*MC_+m]; cc += (float)cm[m]; }
#pragma unroll
    for (int m = 0; m < MT_; ++m) { ti[m] = tab_idx[u*MT_+m]; tm[m] = tab_mask[u*MT_+m]; tc += (float)tm[m]; }
    const float rc = 1.f / fmaxf(cc, 1.f);
    const float rt = 1.f / fmaxf(tc, 1.f);

    const float* fb = feat + (size_t)t * DB2_ * H_;
    const int h = tid * 2;

    float acx = 0.f, acy = 0.f, atx = 0.f, aty = 0.f;
#pragma unroll
    for (int m = 0; m < MC_; ++m) if (cm[m]) {
        const float2 v = *(const float2*)(fb + (size_t)ci[m]*H_ + h);
        acx += v.x; acy += v.y;
    }
#pragma unroll
    for (int m = 0; m < MT_; ++m) if (tm[m]) {
        const float2 v = *(const float2*)(fb + (size_t)ti[m]*H_ + h);
        atx += v.x; aty += v.y;
    }
    const size_t o = ((size_t)(t*U_ + u))*H_ + h;
    *(float2*)(x2 + o) = make_float2(acx*rc, acy*rc);
    *(float2*)(x1 + o) = make_float2(atx*rt, aty*rt);
}

// ---------------------------------------------------------------------------
// Kernels 2-5: fused GRU cell.
// C tile: BM=64 rows x BN=64 gate-cols (x3 gates). BK=32.
// 256 threads, each owns 4x4 outputs per gate.
// HAS_H=false: h=0, write Hout.  HAS_H=true: read Hin, write emb=0.5*(Hin+h').
// ---------------------------------------------------------------------------
#define BM 64
#define BN 64
#define BK 32

template<bool HAS_H>
__global__ __launch_bounds__(256) void gru_cell_kernel(
    const float* __restrict__ X,     // [M_,512]
    const float* __restrict__ Hin,   // [M_,256] or nullptr
    const float* __restrict__ Wih,   // [768,512]
    const float* __restrict__ Whh,   // [768,256]
    const float* __restrict__ bih,   // [768]
    const float* __restrict__ bhh,   // [768]
    float* __restrict__ Hout,        // [M_,256] (HAS_H=false)
    float* __restrict__ emb)         // [M_,512] with col offset applied (HAS_H=true)
{
    __shared__ float At[BK][BM];      // 8 KB
    __shared__ float Bt[BK][3*BN];    // 24 KB

    const int j0 = blockIdx.x * BN;
    const int i0 = blockIdx.y * BM;
    const int t  = threadIdx.x;
    const int tx = t & 15, ty = t >> 4;
    const int lr = t >> 3, lc = (t & 7) * 4;

    float acc[3][4][4] = {};
    float accn[4][4]   = {};

    // ---- phase 1: X @ Wih^T ----
    for (int k0 = 0; k0 < H_; k0 += BK) {
        {
            float4 a0 = *(const float4*)(X + (size_t)(i0+lr   )*H_ + k0 + lc);
            float4 a1 = *(const float4*)(X + (size_t)(i0+lr+32)*H_ + k0 + lc);
            At[lc+0][lr] = a0.x; At[lc+1][lr] = a0.y; At[lc+2][lr] = a0.z; At[lc+3][lr] = a0.w;
            At[lc+0][lr+32] = a1.x; At[lc+1][lr+32] = a1.y; At[lc+2][lr+32] = a1.z; At[lc+3][lr+32] = a1.w;
#pragma unroll
            for (int s = 0; s < 6; ++s) {
                const int wl = lr + 32*s;          // 0..191
                const int g = wl >> 6, c = wl & 63;
                float4 b = *(const float4*)(Wih + (size_t)(g*Hh_ + j0 + c)*H_ + k0 + lc);
                Bt[lc+0][wl] = b.x; Bt[lc+1][wl] = b.y; Bt[lc+2][wl] = b.z; Bt[lc+3][wl] = b.w;
            }
        }
        __syncthreads();
#pragma unroll 8
        for (int kk = 0; kk < BK; ++kk) {
            const float4 av = *(const float4*)&At[kk][ty*4];
            const float a[4] = {av.x, av.y, av.z, av.w};
#pragma unroll
            for (int g = 0; g < 3; ++g) {
                const float4 bv = *(const float4*)&Bt[kk][g*BN + tx*4];
                const float b[4] = {bv.x, bv.y, bv.z, bv.w};
#pragma unroll
                for (int r = 0; r < 4; ++r)
#pragma unroll
                    for (int c = 0; c < 4; ++c)
                        acc[g][r][c] = fmaf(a[r], b[c], acc[g][r][c]);
            }
        }
        __syncthreads();
    }

    // ---- phase 2: Hin @ Whh^T (r,z into acc[0],acc[1]; n into accn) ----
    if (HAS_H) {
        for (int k0 = 0; k0 < Hh_; k0 += BK) {
            {
                float4 a0 = *(const float4*)(Hin + (size_t)(i0+lr   )*Hh_ + k0 + lc);
                float4 a1 = *(const float4*)(Hin + (size_t)(i0+lr+32)*Hh_ + k0 + lc);
                At[lc+0][lr] = a0.x; At[lc+1][lr] = a0.y; At[lc+2][lr] = a0.z; At[lc+3][lr] = a0.w;
                At[lc+0][lr+32] = a1.x; At[lc+1][lr+32] = a1.y; At[lc+2][lr+32] = a1.z; At[lc+3][lr+32] = a1.w;
#pragma unroll
                for (int s = 0; s < 6; ++s) {
                    const int wl = lr + 32*s;
                    const int g = wl >> 6, c = wl & 63;
                    float4 b = *(const float4*)(Whh + (size_t)(g*Hh_ + j0 + c)*Hh_ + k0 + lc);
                    Bt[lc+0][wl] = b.x; Bt[lc+1][wl] = b.y; Bt[lc+2][wl] = b.z; Bt[lc+3][wl] = b.w;
                }
            }
            __syncthreads();
#pragma unroll 8
            for (int kk = 0; kk < BK; ++kk) {
                const float4 av = *(const float4*)&At[kk][ty*4];
                const float a[4] = {av.x, av.y, av.z, av.w};
                {
                    const float4 bv = *(const float4*)&Bt[kk][0*BN + tx*4];
                    const float b[4] = {bv.x, bv.y, bv.z, bv.w};
#pragma unroll
                    for (int r = 0; r < 4; ++r)
#pragma unroll
                        for (int c = 0; c < 4; ++c)
                            acc[0][r][c] = fmaf(a[r], b[c], acc[0][r][c]);
                }
                {
                    const float4 bv = *(const float4*)&Bt[kk][1*BN + tx*4];
                    const float b[4] = {bv.x, bv.y, bv.z, bv.w};
#pragma unroll
                    for (int r = 0; r < 4; ++r)
#pragma unroll
                        for (int c = 0; c < 4; ++c)
                            acc[1][r][c] = fmaf(a[r], b[c], acc[1][r][c]);
                }
                {
                    const float4 bv = *(const float4*)&Bt[kk][2*BN + tx*4];
                    const float b[4] = {bv.x, bv.y, bv.z, bv.w};
#pragma unroll
                    for (int r = 0; r < 4; ++r)
#pragma unroll
                        for (int c = 0; c < 4; ++c)
                            accn[r][c] = fmaf(a[r], b[c], accn[r][c]);
                }
            }
            __syncthreads();
        }
    }

    // ---- epilogue: gates ----
#pragma unroll
    for (int r = 0; r < 4; ++r) {
        const int i = i0 + ty*4 + r;
#pragma unroll
        for (int c = 0; c < 4; ++c) {
            const int j = j0 + tx*4 + c;
            const float xr  = acc[0][r][c] + bih[j]        + bhh[j];
            const float xz  = acc[1][r][c] + bih[Hh_ + j]  + bhh[Hh_ + j];
            const float xin = acc[2][r][c] + bih[2*Hh_ + j];
            const float hn  = accn[r][c]   + bhh[2*Hh_ + j];
            const float rg = sigmoidf_(xr);
            const float zg = sigmoidf_(xz);
            const float ng = tanhf(xin + rg * hn);
            float hprev = 0.f;
            if (HAS_H) hprev = Hin[(size_t)i*Hh_ + j];
            const float hp = (1.f - zg) * ng + zg * hprev;
            if (HAS_H) emb[(size_t)i*H_ + j] = 0.5f * (hprev + hp);
            else       Hout[(size_t)i*Hh_ + j] = hp;
        }
    }
}

// ---------------------------------------------------------------------------
// block reductions
// ---------------------------------------------------------------------------
template<int NT>
__device__ __forceinline__ float block_reduce_max(float v, float* red) {
#pragma unroll
    for (int o = 32; o > 0; o >>= 1) v = fmaxf(v, __shfl_down(v, o));
    const int wid = threadIdx.x >> 6;
    if ((threadIdx.x & 63) == 0) red[wid] = v;
    __syncthreads();
    if (threadIdx.x == 0) {
        float m = red[0];
#pragma unroll
        for (int i = 1; i < NT/64; ++i) m = fmaxf(m, red[i]);
        red[0] = m;
    }
    __syncthreads();
    const float r = red[0];
    __syncthreads();
    return r;
}

template<int NT>
__device__ __forceinline__ float block_reduce_sum(float v, float* red) {
#pragma unroll
    for (int o = 32; o > 0; o >>= 1) v += __shfl_down(v, o);
    const int wid = threadIdx.x >> 6;
    if ((threadIdx.x & 63) == 0) red[wid] = v;
    __syncthreads();
    if (threadIdx.x == 0) {
        float m = red[0];
#pragma unroll
        for (int i = 1; i < NT/64; ++i) m += red[i];
        red[0] = m;
    }
    __syncthreads();
    const float r = red[0];
    __syncthreads();
    return r;
}

// ---------------------------------------------------------------------------
// Kernel 6: attention per t.  512 threads.
// ---------------------------------------------------------------------------
__global__ __launch_bounds__(512) void attn_kernel(
    const float* __restrict__ db, const float* __restrict__ key,
    const int* __restrict__ attn_mask, float* __restrict__ attn)
{
    __shared__ float sk[H_];
    __shared__ float sl[U_];
    __shared__ float red[8];
    const int t = blockIdx.x;
    const int tid = threadIdx.x;

    if (tid < H_) sk[tid] = key[t*H_ + tid];
    __syncthreads();

#pragma unroll
    for (int uu = 0; uu < U_/512; ++uu) {
        const int u = tid + uu*512;
        const float* row = db + ((size_t)t*U_ + u)*H_;
        float s = 0.f;
        for (int k = 0; k < H_; ++k) s = fmaf(sk[k], row[k], s);
        sl[u] = attn_mask[t*U_ + u] ? s : -1e9f;
    }
    __syncthreads();

    float m = fmaxf(sl[tid], sl[tid + 512]);
    m = block_reduce_max<512>(m, red);

    const float e0 = expf(sl[tid] - m), e1 = expf(sl[tid+512] - m);
    sl[tid] = e0; sl[tid+512] = e1;
    float s = block_reduce_sum<512>(e0 + e1, red);
    const float inv = 1.f / s;
    __syncthreads();

    // weighted sum over u -> attn[t, h], one h per thread
    float a = 0.f;
    for (int u = 0; u < U_; ++u)
        a = fmaf(sl[u], db[((size_t)t*U_ + u)*H_ + tid], a);
    attn[t*H_ + tid] = a * inv;
}

// ---------------------------------------------------------------------------
// Kernel 7: ff = tanh((final_feature + attn) @ Wb^T + bb).  block per row.
// ---------------------------------------------------------------------------
__global__ __launch_bounds__(256) void ff_kernel(
    const float* __restrict__ finf, const float* __restrict__ attn,
    const float* __restrict__ Wb, const float* __restrict__ bb,
    float* __restrict__ ff)
{
    __shared__ float sf[H_];
    const int row = blockIdx.x;       // t*64+l
    const int t = row >> 6;
    const int tid = threadIdx.x;

    for (int h = tid; h < H_; h += 256)
        sf[h] = finf[(size_t)row*H_ + h] + attn[t*H_ + h];
    __syncthreads();

#pragma unroll
    for (int jj = 0; jj < H_/256; ++jj) {
        const int j = tid + jj*256;
        const float* w = Wb + (size_t)j*H_;
        float s = bb[j];
        for (int k = 0; k < H_; ++k) s = fmaf(sf[k], w[k], s);
        ff[(size_t)row*H_ + j] = tanhf(s);
    }
}

// ---------------------------------------------------------------------------
// Kernel 8: per (t,l): 1088 logits + log_softmax
// ---------------------------------------------------------------------------
__global__ __launch_bounds__(256) void out_kernel(
    const float* __restrict__ ff, const float* __restrict__ db,
    const float* __restrict__ Kemb, float* __restrict__ out)
{
    __shared__ float sf[H_];
    __shared__ float sl[U_ + K_];
    __shared__ float red[4];
    const int row = blockIdx.x;       // t*64+l
    const int t = row >> 6;
    const int tid = threadIdx.x;

    for (int h = tid; h < H_; h += 256) sf[h] = ff[(size_t)row*H_ + h];
    __syncthreads();

    for (int idx = tid; idx < U_ + K_; idx += 256) {
        const float* v = (idx < U_) ? (db + ((size_t)t*U_ + idx)*H_)
                                    : (Kemb + (size_t)(idx - U_)*H_);
        float s = 0.f;
        for (int k = 0; k < H_; ++k) s = fmaf(sf[k], v[k], s);
        sl[idx] = s;
    }
    __syncthreads();

    float m = -3.4e38f;
    for (int idx = tid; idx < U_ + K_; idx += 256) m = fmaxf(m, sl[idx]);
    m = block_reduce_max<256>(m, red);

    float s = 0.f;
    for (int idx = tid; idx < U_ + K_; idx += 256) s += expf(sl[idx] - m);
    s = block_reduce_sum<256>(s, red);
    const float lse = m + logf(s);

    for (int idx = tid; idx < U_ + K_; idx += 256)
        out[(size_t)row*(U_ + K_) + idx] = sl[idx] - lse;
}

// ---------------------------------------------------------------------------
extern "C" void kernel_launch(void* const* d_in, const int* in_sizes, int n_in,
                              void* d_out, int out_size, void* d_ws, size_t ws_size,
                              hipStream_t stream)
{
    const float* feat  = (const float*)d_in[0];
    const float* key   = (const float*)d_in[1];
    const float* finf  = (const float*)d_in[2];
    const float* Wih_f = (const float*)d_in[3];
    const float* Whh_f = (const float*)d_in[4];
    const float* bih_f = (const float*)d_in[5];
    const float* bhh_f = (const float*)d_in[6];
    const float* Wih_b = (const float*)d_in[7];
    const float* Whh_b = (const float*)d_in[8];
    const float* bih_b = (const float*)d_in[9];
    const float* bhh_b = (const float*)d_in[10];
    const float* Wb    = (const float*)d_in[11];
    const float* bb    = (const float*)d_in[12];
    const float* Kemb  = (const float*)d_in[13];
    const int* col_idx  = (const int*)d_in[14];
    const int* col_mask = (const int*)d_in[15];
    const int* tab_idx  = (const int*)d_in[16];
    const int* tab_mask = (const int*)d_in[17];
    const int* attn_mask= (const int*)d_in[18];
    float* out = (float*)d_out;

    float* ws = (float*)d_ws;
    float* x1   = ws;                                  // [M_,512] tab_feat
    float* x2   = x1 + (size_t)M_*H_;                  // [M_,512] col_feat
    float* f1   = x2 + (size_t)M_*H_;                  // [M_,256]
    float* b1   = f1 + (size_t)M_*Hh_;                 // [M_,256]
    float* db   = b1 + (size_t)M_*Hh_;                 // [M_,512] db_emb
    float* attn = db + (size_t)M_*H_;                  // [T_,512]
    float* ffb  = attn + (size_t)T_*H_;                // [T_*L_,512]

    meanpool_kernel<<<dim3(U_, T_), 256, 0, stream>>>(
        feat, col_idx, col_mask, tab_idx, tab_mask, x1, x2);

    dim3 gg(Hh_/BN, M_/BM);   // (4, 256)
    gru_cell_kernel<false><<<gg, 256, 0, stream>>>(x1, nullptr, Wih_f, Whh_f, bih_f, bhh_f, f1, nullptr);
    gru_cell_kernel<false><<<gg, 256, 0, stream>>>(x2, nullptr, Wih_b, Whh_b, bih_b, bhh_b, b1, nullptr);
    gru_cell_kernel<true ><<<gg, 256, 0, stream>>>(x2, f1, Wih_f, Whh_f, bih_f, bhh_f, nullptr, db);
    gru_cell_kernel<true ><<<gg, 256, 0, stream>>>(x1, b1, Wih_b, Whh_b, bih_b, bhh_b, nullptr, db + Hh_);

    attn_kernel<<<T_, 512, 0, stream>>>(db, key, attn_mask, attn);
    ff_kernel<<<T_*L_, 256, 0, stream>>>(finf, attn, Wb, bb, ffb);
    out_kernel<<<T_*L_, 256, 0, stream>>>(ffb, db, Kemb, out);
}

// Round 2
// 818.831 us; speedup vs baseline: 1.8608x; 1.8608x over previous
//
#include <hip/hip_runtime.h>
#include <math.h>

#define T_  16
#define DB2_ 512
#define H_  512
#define Hh_ 256
#define U_  1024
#define MC_ 8
#define MT_ 4
#define L_  64
#define K_  64
#define M_  (T_*U_)   // 16384

#define BM 128
#define BNG 64
#define BK 64
#define S0_ (768*512)
#define S1_ (768*256)

typedef __attribute__((ext_vector_type(8))) short bf16x8;
typedef __attribute__((ext_vector_type(4))) float f32x4;

__device__ __forceinline__ float sigmoidf_(float x) { return 1.f / (1.f + expf(-x)); }

__device__ __forceinline__ ushort f2bf(float f) {
    union { float f; unsigned u; } v; v.f = f;
    const unsigned r = (v.u + 0x7FFFu + ((v.u >> 16) & 1u)) >> 16;
    return (ushort)r;
}

__device__ __forceinline__ void gload16(const void* g, void* l) {
    __builtin_amdgcn_global_load_lds(
        (const __attribute__((address_space(1))) void*)g,
        (__attribute__((address_space(3))) void*)l, 16, 0, 0);
}

// ---------------------------------------------------------------------------
// Kernel 0: convert the 4 GRU weight matrices to bf16 (concat layout in ws)
// segments: [0,S0) Wih_f | [S0,S0+S1) Whh_f | [..) Wih_b | [..) Whh_b
// ---------------------------------------------------------------------------
__global__ __launch_bounds__(256) void wcvt_kernel(
    const float* __restrict__ w0, const float* __restrict__ w1,
    const float* __restrict__ w2, const float* __restrict__ w3,
    ushort* __restrict__ dst)
{
    const int idx = (blockIdx.x * 256 + threadIdx.x) * 4;
    const float* src; int local;
    if      (idx < S0_)            { src = w0; local = idx; }
    else if (idx < S0_ + S1_)      { src = w1; local = idx - S0_; }
    else if (idx < 2*S0_ + S1_)    { src = w2; local = idx - S0_ - S1_; }
    else                           { src = w3; local = idx - 2*S0_ - S1_; }
    const float4 v = *(const float4*)(src + local);
    ushort4 o; o.x = f2bf(v.x); o.y = f2bf(v.y); o.z = f2bf(v.z); o.w = f2bf(v.w);
    *(ushort4*)(dst + idx) = o;
}

// ---------------------------------------------------------------------------
// Kernel 1: masked mean pooling -> x1 (tab), x2 (col) in bf16
// grid (U, T), 256 threads, 2 h per thread
// ---------------------------------------------------------------------------
__global__ __launch_bounds__(256) void meanpool_kernel(
    const float* __restrict__ feat,
    const int* __restrict__ col_idx, const int* __restrict__ col_mask,
    const int* __restrict__ tab_idx, const int* __restrict__ tab_mask,
    ushort* __restrict__ x1, ushort* __restrict__ x2)
{
    const int u = blockIdx.x;
    const int t = blockIdx.y;
    const int tid = threadIdx.x;

    int ci[MC_], cm[MC_], ti[MT_], tm[MT_];
    float cc = 0.f, tc = 0.f;
#pragma unroll
    for (int m = 0; m < MC_; ++m) { ci[m] = col_idx[u*MC_+m]; cm[m] = col_mask[u*MC_+m]; cc += (float)cm[m]; }
#pragma unroll
    for (int m = 0; m < MT_; ++m) { ti[m] = tab_idx[u*MT_+m]; tm[m] = tab_mask[u*MT_+m]; tc += (float)tm[m]; }
    const float rc = 1.f / fmaxf(cc, 1.f);
    const float rt = 1.f / fmaxf(tc, 1.f);

    const float* fb = feat + (size_t)t * DB2_ * H_;
    const int h = tid * 2;

    float acx = 0.f, acy = 0.f, atx = 0.f, aty = 0.f;
#pragma unroll
    for (int m = 0; m < MC_; ++m) if (cm[m]) {
        const float2 v = *(const float2*)(fb + (size_t)ci[m]*H_ + h);
        acx += v.x; acy += v.y;
    }
#pragma unroll
    for (int m = 0; m < MT_; ++m) if (tm[m]) {
        const float2 v = *(const float2*)(fb + (size_t)ti[m]*H_ + h);
        atx += v.x; aty += v.y;
    }
    const size_t o = ((size_t)(t*U_ + u))*H_ + h;
    ushort2 c2; c2.x = f2bf(acx*rc); c2.y = f2bf(acy*rc);
    ushort2 t2; t2.x = f2bf(atx*rt); t2.y = f2bf(aty*rt);
    *(ushort2*)(x2 + o) = c2;
    *(ushort2*)(x1 + o) = t2;
}

// ---------------------------------------------------------------------------
// GRU cell via MFMA. Block: 128 rows x 64 gate-cols x 3 gates. BK=64.
// 4 waves in 2x2; per wave 64x32 per gate; frags 4x2 of 16x16, K-sub 2x32.
// ---------------------------------------------------------------------------
__device__ __forceinline__ void stage_tiles(
    const ushort* __restrict__ Xb, int ldx,
    const ushort* __restrict__ Wb, int ldw,
    int i0, int j0, int k0,
    ushort* AsBase, ushort* BsBase, int lane, int wid)
{
#pragma unroll
    for (int cc = wid; cc < 40; cc += 4) {
        if (cc < 16) {
            const ushort* g = Xb + (size_t)(i0 + cc*8 + (lane>>3))*ldx + k0 + (lane&7)*8;
            gload16(g, AsBase + cc*512);
        } else {
            const int c = cc - 16;
            const int rowB = c*8 + (lane>>3);
            const ushort* g = Wb + (size_t)((rowB>>6)*Hh_ + j0 + (rowB&63))*ldw + k0 + (lane&7)*8;
            gload16(g, BsBase + c*512);
        }
    }
}

template<int GN>
__device__ __forceinline__ void compute_tile(
    f32x4 (&acc)[4][4][2],
    const ushort (&As)[BM][BK], const ushort (&Bs)[192][BK],
    int lane, int wm, int wn)
{
#pragma unroll
    for (int s = 0; s < 2; ++s) {
        bf16x8 af[4];
#pragma unroll
        for (int fm = 0; fm < 4; ++fm)
            af[fm] = *(const bf16x8*)&As[wm*64 + fm*16 + (lane&15)][s*32 + (lane>>4)*8];
#pragma unroll
        for (int g = 0; g < 3; ++g) {
            const int gi = (g == 2) ? GN : g;
#pragma unroll
            for (int fn = 0; fn < 2; ++fn) {
                const bf16x8 bv = *(const bf16x8*)&Bs[g*64 + wn*32 + fn*16 + (lane&15)][s*32 + (lane>>4)*8];
#pragma unroll
                for (int fm = 0; fm < 4; ++fm)
                    acc[gi][fm][fn] = __builtin_amdgcn_mfma_f32_16x16x32_bf16(
                        af[fm], bv, acc[gi][fm][fn], 0, 0, 0);
            }
        }
    }
}

template<bool HAS_H>
__global__ __launch_bounds__(256) void gru_mfma_kernel(
    const ushort* __restrict__ Xb,      // [M,512] bf16
    const ushort* __restrict__ Hb,      // [M,256] bf16 (HAS_H)
    const float*  __restrict__ Hf,      // [M,256] f32  (HAS_H)
    const ushort* __restrict__ Wihb,    // [768,512] bf16
    const ushort* __restrict__ Whhb,    // [768,256] bf16
    const float* __restrict__ bih, const float* __restrict__ bhh,
    float* __restrict__ Hout_f, ushort* __restrict__ Hout_b, // !HAS_H
    float* __restrict__ emb)            // HAS_H: db base + col offset
{
    __shared__ __align__(16) ushort As[BM][BK];   // 16 KB
    __shared__ __align__(16) ushort Bs[192][BK];  // 24 KB

    const int tid = threadIdx.x;
    const int lane = tid & 63, wid = tid >> 6;
    const int wm = wid >> 1, wn = wid & 1;
    const int i0 = blockIdx.y * BM;
    const int j0 = blockIdx.x * BNG;

    f32x4 acc[4][4][2] = {};   // [r,z,n_ih | n_hh][fm][fn]

    for (int k0 = 0; k0 < H_; k0 += BK) {
        stage_tiles(Xb, H_, Wihb, H_, i0, j0, k0, &As[0][0], &Bs[0][0], lane, wid);
        __syncthreads();
        compute_tile<2>(acc, As, Bs, lane, wm, wn);
        __syncthreads();
    }
    if (HAS_H) {
        for (int k0 = 0; k0 < Hh_; k0 += BK) {
            stage_tiles(Hb, Hh_, Whhb, Hh_, i0, j0, k0, &As[0][0], &Bs[0][0], lane, wid);
            __syncthreads();
            compute_tile<3>(acc, As, Bs, lane, wm, wn);
            __syncthreads();
        }
    }

#pragma unroll
    for (int fn = 0; fn < 2; ++fn) {
        const int j = j0 + wn*32 + fn*16 + (lane & 15);
        const float bri = bih[j],       brh = bhh[j];
        const float bzi = bih[Hh_ + j], bzh = bhh[Hh_ + j];
        const float bni = bih[2*Hh_+j], bnh = bhh[2*Hh_ + j];
#pragma unroll
        for (int fm = 0; fm < 4; ++fm) {
#pragma unroll
            for (int r = 0; r < 4; ++r) {
                const int i = i0 + wm*64 + fm*16 + (lane >> 4)*4 + r;
                const float xr = acc[0][fm][fn][r] + bri + brh;
                const float xz = acc[1][fm][fn][r] + bzi + bzh;
                const float xn = acc[2][fm][fn][r] + bni;
                float hn = bnh, hprev = 0.f;
                if (HAS_H) { hn += acc[3][fm][fn][r]; hprev = Hf[(size_t)i*Hh_ + j]; }
                const float rg = sigmoidf_(xr);
                const float zg = sigmoidf_(xz);
                const float ng = tanhf(xn + rg * hn);
                const float hp = (1.f - zg) * ng + zg * hprev;
                if (HAS_H) {
                    emb[(size_t)i*H_ + j] = 0.5f * (hprev + hp);
                } else {
                    Hout_f[(size_t)i*Hh_ + j] = hp;
                    Hout_b[(size_t)i*Hh_ + j] = f2bf(hp);
                }
            }
        }
    }
}

// ---------------------------------------------------------------------------
// block reductions
// ---------------------------------------------------------------------------
template<int NT>
__device__ __forceinline__ float block_reduce_max(float v, float* red) {
#pragma unroll
    for (int o = 32; o > 0; o >>= 1) v = fmaxf(v, __shfl_down(v, o));
    const int wid = threadIdx.x >> 6;
    if ((threadIdx.x & 63) == 0) red[wid] = v;
    __syncthreads();
    if (threadIdx.x == 0) {
        float m = red[0];
#pragma unroll
        for (int i = 1; i < NT/64; ++i) m = fmaxf(m, red[i]);
        red[0] = m;
    }
    __syncthreads();
    const float r = red[0];
    __syncthreads();
    return r;
}

template<int NT>
__device__ __forceinline__ float block_reduce_sum(float v, float* red) {
#pragma unroll
    for (int o = 32; o > 0; o >>= 1) v += __shfl_down(v, o);
    const int wid = threadIdx.x >> 6;
    if ((threadIdx.x & 63) == 0) red[wid] = v;
    __syncthreads();
    if (threadIdx.x == 0) {
        float m = red[0];
#pragma unroll
        for (int i = 1; i < NT/64; ++i) m += red[i];
        red[0] = m;
    }
    __syncthreads();
    const float r = red[0];
    __syncthreads();
    return r;
}

// ---------------------------------------------------------------------------
// attention per t. 512 threads.
// ---------------------------------------------------------------------------
__global__ __launch_bounds__(512) void attn_kernel(
    const float* __restrict__ db, const float* __restrict__ key,
    const int* __restrict__ attn_mask, float* __restrict__ attn)
{
    __shared__ float sk[H_];
    __shared__ float sl[U_];
    __shared__ float red[8];
    const int t = blockIdx.x;
    const int tid = threadIdx.x;

    if (tid < H_) sk[tid] = key[t*H_ + tid];
    __syncthreads();

#pragma unroll
    for (int uu = 0; uu < U_/512; ++uu) {
        const int u = tid + uu*512;
        const float* row = db + ((size_t)t*U_ + u)*H_;
        float s = 0.f;
        for (int k = 0; k < H_; ++k) s = fmaf(sk[k], row[k], s);
        sl[u] = attn_mask[t*U_ + u] ? s : -1e9f;
    }
    __syncthreads();

    float m = fmaxf(sl[tid], sl[tid + 512]);
    m = block_reduce_max<512>(m, red);

    const float e0 = expf(sl[tid] - m), e1 = expf(sl[tid+512] - m);
    sl[tid] = e0; sl[tid+512] = e1;
    float s = block_reduce_sum<512>(e0 + e1, red);
    const float inv = 1.f / s;
    __syncthreads();

    float a = 0.f;
    for (int u = 0; u < U_; ++u)
        a = fmaf(sl[u], db[((size_t)t*U_ + u)*H_ + tid], a);
    attn[t*H_ + tid] = a * inv;
}

// ---------------------------------------------------------------------------
// ff = tanh((final_feature + attn) @ Wb^T + bb). block per row.
// ---------------------------------------------------------------------------
__global__ __launch_bounds__(256) void ff_kernel(
    const float* __restrict__ finf, const float* __restrict__ attn,
    const float* __restrict__ Wb, const float* __restrict__ bb,
    float* __restrict__ ff)
{
    __shared__ float sf[H_];
    const int row = blockIdx.x;       // t*64+l
    const int t = row >> 6;
    const int tid = threadIdx.x;

    for (int h = tid; h < H_; h += 256)
        sf[h] = finf[(size_t)row*H_ + h] + attn[t*H_ + h];
    __syncthreads();

#pragma unroll
    for (int jj = 0; jj < H_/256; ++jj) {
        const int j = tid + jj*256;
        const float* w = Wb + (size_t)j*H_;
        float s = bb[j];
        for (int k = 0; k < H_; ++k) s = fmaf(sf[k], w[k], s);
        ff[(size_t)row*H_ + j] = tanhf(s);
    }
}

// ---------------------------------------------------------------------------
// per (t,l): 1088 logits + log_softmax
// ---------------------------------------------------------------------------
__global__ __launch_bounds__(256) void out_kernel(
    const float* __restrict__ ff, const float* __restrict__ db,
    const float* __restrict__ Kemb, float* __restrict__ out)
{
    __shared__ float sf[H_];
    __shared__ float sl[U_ + K_];
    __shared__ float red[4];
    const int row = blockIdx.x;       // t*64+l
    const int t = row >> 6;
    const int tid = threadIdx.x;

    for (int h = tid; h < H_; h += 256) sf[h] = ff[(size_t)row*H_ + h];
    __syncthreads();

    for (int idx = tid; idx < U_ + K_; idx += 256) {
        const float* v = (idx < U_) ? (db + ((size_t)t*U_ + idx)*H_)
                                    : (Kemb + (size_t)(idx - U_)*H_);
        float s = 0.f;
        for (int k = 0; k < H_; ++k) s = fmaf(sf[k], v[k], s);
        sl[idx] = s;
    }
    __syncthreads();

    float m = -3.4e38f;
    for (int idx = tid; idx < U_ + K_; idx += 256) m = fmaxf(m, sl[idx]);
    m = block_reduce_max<256>(m, red);

    float s = 0.f;
    for (int idx = tid; idx < U_ + K_; idx += 256) s += expf(sl[idx] - m);
    s = block_reduce_sum<256>(s, red);
    const float lse = m + logf(s);

    for (int idx = tid; idx < U_ + K_; idx += 256)
        out[(size_t)row*(U_ + K_) + idx] = sl[idx] - lse;
}

// ---------------------------------------------------------------------------
extern "C" void kernel_launch(void* const* d_in, const int* in_sizes, int n_in,
                              void* d_out, int out_size, void* d_ws, size_t ws_size,
                              hipStream_t stream)
{
    const float* feat  = (const float*)d_in[0];
    const float* key   = (const float*)d_in[1];
    const float* finf  = (const float*)d_in[2];
    const float* Wih_f = (const float*)d_in[3];
    const float* Whh_f = (const float*)d_in[4];
    const float* bih_f = (const float*)d_in[5];
    const float* bhh_f = (const float*)d_in[6];
    const float* Wih_b = (const float*)d_in[7];
    const float* Whh_b = (const float*)d_in[8];
    const float* bih_b = (const float*)d_in[9];
    const float* bhh_b = (const float*)d_in[10];
    const float* Wb    = (const float*)d_in[11];
    const float* bb    = (const float*)d_in[12];
    const float* Kemb  = (const float*)d_in[13];
    const int* col_idx  = (const int*)d_in[14];
    const int* col_mask = (const int*)d_in[15];
    const int* tab_idx  = (const int*)d_in[16];
    const int* tab_mask = (const int*)d_in[17];
    const int* attn_mask= (const int*)d_in[18];
    float* out = (float*)d_out;

    char* p = (char*)d_ws;
    ushort* wbf  = (ushort*)p;                 p += (size_t)2*(S0_+S1_)*2;     // 2.36 MB
    ushort* x1b  = (ushort*)p;                 p += (size_t)M_*H_*2;           // 16.8 MB
    ushort* x2b  = (ushort*)p;                 p += (size_t)M_*H_*2;
    float*  f1f  = (float*)p;                  p += (size_t)M_*Hh_*4;
    ushort* f1b  = (ushort*)p;                 p += (size_t)M_*Hh_*2;
    float*  b1f  = (float*)p;                  p += (size_t)M_*Hh_*4;
    ushort* b1b  = (ushort*)p;                 p += (size_t)M_*Hh_*2;
    float*  db   = (float*)p;                  p += (size_t)M_*H_*4;           // 33.6 MB
    float*  attn = (float*)p;                  p += (size_t)T_*H_*4;
    float*  ffb  = (float*)p;                  p += (size_t)T_*L_*H_*4;

    const ushort* Wihf_b = wbf;
    const ushort* Whhf_b = wbf + S0_;
    const ushort* Wihb_b = wbf + S0_ + S1_;
    const ushort* Whhb_b = wbf + 2*S0_ + S1_;

    wcvt_kernel<<<(2*(S0_+S1_))/1024, 256, 0, stream>>>(Wih_f, Whh_f, Wih_b, Whh_b, wbf);

    meanpool_kernel<<<dim3(U_, T_), 256, 0, stream>>>(
        feat, col_idx, col_mask, tab_idx, tab_mask, x1b, x2b);

    dim3 gg(Hh_/BNG, M_/BM);   // (4, 128)
    gru_mfma_kernel<false><<<gg, 256, 0, stream>>>(x1b, nullptr, nullptr, Wihf_b, Whhf_b,
                                                   bih_f, bhh_f, f1f, f1b, nullptr);
    gru_mfma_kernel<false><<<gg, 256, 0, stream>>>(x2b, nullptr, nullptr, Wihb_b, Whhb_b,
                                                   bih_b, bhh_b, b1f, b1b, nullptr);
    gru_mfma_kernel<true ><<<gg, 256, 0, stream>>>(x2b, f1b, f1f, Wihf_b, Whhf_b,
                                                   bih_f, bhh_f, nullptr, nullptr, db);
    gru_mfma_kernel<true ><<<gg, 256, 0, stream>>>(x1b, b1b, b1f, Wihb_b, Whhb_b,
                                                   bih_b, bhh_b, nullptr, nullptr, db + Hh_);

    attn_kernel<<<T_, 512, 0, stream>>>(db, key, attn_mask, attn);
    ff_kernel<<<T_*L_, 256, 0, stream>>>(finf, attn, Wb, bb, ffb);
    out_kernel<<<T_*L_, 256, 0, stream>>>(ffb, db, Kemb, out);
}

// Round 3
// 462.426 us; speedup vs baseline: 3.2949x; 1.7707x over previous
//
#include <hip/hip_runtime.h>
#include <math.h>

#define T_  16
#define DB2_ 512
#define H_  512
#define Hh_ 256
#define U_  1024
#define MC_ 8
#define MT_ 4
#define L_  64
#define K_  64
#define M_  (T_*U_)   // 16384

#define BM 128
#define BNG 64
#define BK 64
#define S0_ (768*512)
#define S1_ (768*256)
#define WB_ (512*512)
#define KE_ (64*512)

typedef __attribute__((ext_vector_type(8))) short bf16x8;
typedef __attribute__((ext_vector_type(4))) float f32x4;

__device__ __forceinline__ float sigmoidf_(float x) { return 1.f / (1.f + expf(-x)); }

__device__ __forceinline__ ushort f2bf(float f) {
    union { float f; unsigned u; } v; v.f = f;
    const unsigned r = (v.u + 0x7FFFu + ((v.u >> 16) & 1u)) >> 16;
    return (ushort)r;
}
__device__ __forceinline__ float bf2f(ushort u) {
    union { unsigned u; float f; } v; v.u = ((unsigned)u) << 16; return v.f;
}

__device__ __forceinline__ void gload16(const void* g, void* l) {
    __builtin_amdgcn_global_load_lds(
        (const __attribute__((address_space(1))) void*)g,
        (__attribute__((address_space(3))) void*)l, 16, 0, 0);
}

// ---------------------------------------------------------------------------
// Kernel 0: convert weights to bf16: Wih_f|Whh_f|Wih_b|Whh_b|Wb|Kemb
// ---------------------------------------------------------------------------
__global__ __launch_bounds__(256) void wcvt_kernel(
    const float* __restrict__ w0, const float* __restrict__ w1,
    const float* __restrict__ w2, const float* __restrict__ w3,
    const float* __restrict__ w4, const float* __restrict__ w5,
    ushort* __restrict__ dst)
{
    const int idx = (blockIdx.x * 256 + threadIdx.x) * 4;
    const float* src; int local;
    if      (idx < S0_)                  { src = w0; local = idx; }
    else if (idx < S0_ + S1_)            { src = w1; local = idx - S0_; }
    else if (idx < 2*S0_ + S1_)          { src = w2; local = idx - S0_ - S1_; }
    else if (idx < 2*S0_ + 2*S1_)        { src = w3; local = idx - 2*S0_ - S1_; }
    else if (idx < 2*S0_ + 2*S1_ + WB_)  { src = w4; local = idx - 2*S0_ - 2*S1_; }
    else                                 { src = w5; local = idx - 2*S0_ - 2*S1_ - WB_; }
    const float4 v = *(const float4*)(src + local);
    ushort4 o; o.x = f2bf(v.x); o.y = f2bf(v.y); o.z = f2bf(v.z); o.w = f2bf(v.w);
    *(ushort4*)(dst + idx) = o;
}

// ---------------------------------------------------------------------------
// Kernel 1: masked mean pooling -> x1 (tab), x2 (col) in bf16
// ---------------------------------------------------------------------------
__global__ __launch_bounds__(256) void meanpool_kernel(
    const float* __restrict__ feat,
    const int* __restrict__ col_idx, const int* __restrict__ col_mask,
    const int* __restrict__ tab_idx, const int* __restrict__ tab_mask,
    ushort* __restrict__ x1, ushort* __restrict__ x2)
{
    const int u = blockIdx.x;
    const int t = blockIdx.y;
    const int tid = threadIdx.x;

    int ci[MC_], cm[MC_], ti[MT_], tm[MT_];
    float cc = 0.f, tc = 0.f;
#pragma unroll
    for (int m = 0; m < MC_; ++m) { ci[m] = col_idx[u*MC_+m]; cm[m] = col_mask[u*MC_+m]; cc += (float)cm[m]; }
#pragma unroll
    for (int m = 0; m < MT_; ++m) { ti[m] = tab_idx[u*MT_+m]; tm[m] = tab_mask[u*MT_+m]; tc += (float)tm[m]; }
    const float rc = 1.f / fmaxf(cc, 1.f);
    const float rt = 1.f / fmaxf(tc, 1.f);

    const float* fb = feat + (size_t)t * DB2_ * H_;
    const int h = tid * 2;

    float acx = 0.f, acy = 0.f, atx = 0.f, aty = 0.f;
#pragma unroll
    for (int m = 0; m < MC_; ++m) if (cm[m]) {
        const float2 v = *(const float2*)(fb + (size_t)ci[m]*H_ + h);
        acx += v.x; acy += v.y;
    }
#pragma unroll
    for (int m = 0; m < MT_; ++m) if (tm[m]) {
        const float2 v = *(const float2*)(fb + (size_t)ti[m]*H_ + h);
        atx += v.x; aty += v.y;
    }
    const size_t o = ((size_t)(t*U_ + u))*H_ + h;
    ushort2 c2; c2.x = f2bf(acx*rc); c2.y = f2bf(acy*rc);
    ushort2 t2; t2.x = f2bf(atx*rt); t2.y = f2bf(aty*rt);
    *(ushort2*)(x2 + o) = c2;
    *(ushort2*)(x1 + o) = t2;
}

// ---------------------------------------------------------------------------
// GRU cell via MFMA. Block: 128 rows x 64 gate-cols x 3 gates. BK=64.
// ---------------------------------------------------------------------------
__device__ __forceinline__ void stage_tiles(
    const ushort* __restrict__ Xb, int ldx,
    const ushort* __restrict__ Wb, int ldw,
    int i0, int j0, int k0,
    ushort* AsBase, ushort* BsBase, int lane, int wid)
{
#pragma unroll
    for (int cc = wid; cc < 40; cc += 4) {
        if (cc < 16) {
            const ushort* g = Xb + (size_t)(i0 + cc*8 + (lane>>3))*ldx + k0 + (lane&7)*8;
            gload16(g, AsBase + cc*512);
        } else {
            const int c = cc - 16;
            const int rowB = c*8 + (lane>>3);
            const ushort* g = Wb + (size_t)((rowB>>6)*Hh_ + j0 + (rowB&63))*ldw + k0 + (lane&7)*8;
            gload16(g, BsBase + c*512);
        }
    }
}

template<int GN>
__device__ __forceinline__ void compute_tile(
    f32x4 (&acc)[4][4][2],
    const ushort (&As)[BM][BK], const ushort (&Bs)[192][BK],
    int lane, int wm, int wn)
{
#pragma unroll
    for (int s = 0; s < 2; ++s) {
        bf16x8 af[4];
#pragma unroll
        for (int fm = 0; fm < 4; ++fm)
            af[fm] = *(const bf16x8*)&As[wm*64 + fm*16 + (lane&15)][s*32 + (lane>>4)*8];
#pragma unroll
        for (int g = 0; g < 3; ++g) {
            const int gi = (g == 2) ? GN : g;
#pragma unroll
            for (int fn = 0; fn < 2; ++fn) {
                const bf16x8 bv = *(const bf16x8*)&Bs[g*64 + wn*32 + fn*16 + (lane&15)][s*32 + (lane>>4)*8];
#pragma unroll
                for (int fm = 0; fm < 4; ++fm)
                    acc[gi][fm][fn] = __builtin_amdgcn_mfma_f32_16x16x32_bf16(
                        af[fm], bv, acc[gi][fm][fn], 0, 0, 0);
            }
        }
    }
}

template<bool HAS_H>
__global__ __launch_bounds__(256) void gru_mfma_kernel(
    const ushort* __restrict__ Xb,      // [M,512] bf16
    const ushort* __restrict__ Hb,      // [M,256] bf16 (HAS_H)
    const float*  __restrict__ Hf,      // [M,256] f32  (HAS_H)
    const ushort* __restrict__ Wihb,    // [768,512] bf16
    const ushort* __restrict__ Whhb,    // [768,256] bf16
    const float* __restrict__ bih, const float* __restrict__ bhh,
    float* __restrict__ Hout_f, ushort* __restrict__ Hout_b, // !HAS_H
    ushort* __restrict__ emb_b)         // HAS_H: dbb base + col offset (bf16)
{
    __shared__ __align__(16) ushort As[BM][BK];   // 16 KB
    __shared__ __align__(16) ushort Bs[192][BK];  // 24 KB

    const int tid = threadIdx.x;
    const int lane = tid & 63, wid = tid >> 6;
    const int wm = wid >> 1, wn = wid & 1;
    const int i0 = blockIdx.y * BM;
    const int j0 = blockIdx.x * BNG;

    f32x4 acc[4][4][2] = {};   // [r,z,n_ih | n_hh][fm][fn]

    for (int k0 = 0; k0 < H_; k0 += BK) {
        stage_tiles(Xb, H_, Wihb, H_, i0, j0, k0, &As[0][0], &Bs[0][0], lane, wid);
        __syncthreads();
        compute_tile<2>(acc, As, Bs, lane, wm, wn);
        __syncthreads();
    }
    if (HAS_H) {
        for (int k0 = 0; k0 < Hh_; k0 += BK) {
            stage_tiles(Hb, Hh_, Whhb, Hh_, i0, j0, k0, &As[0][0], &Bs[0][0], lane, wid);
            __syncthreads();
            compute_tile<3>(acc, As, Bs, lane, wm, wn);
            __syncthreads();
        }
    }

#pragma unroll
    for (int fn = 0; fn < 2; ++fn) {
        const int j = j0 + wn*32 + fn*16 + (lane & 15);
        const float bri = bih[j],       brh = bhh[j];
        const float bzi = bih[Hh_ + j], bzh = bhh[Hh_ + j];
        const float bni = bih[2*Hh_+j], bnh = bhh[2*Hh_ + j];
#pragma unroll
        for (int fm = 0; fm < 4; ++fm) {
#pragma unroll
            for (int r = 0; r < 4; ++r) {
                const int i = i0 + wm*64 + fm*16 + (lane >> 4)*4 + r;
                const float xr = acc[0][fm][fn][r] + bri + brh;
                const float xz = acc[1][fm][fn][r] + bzi + bzh;
                const float xn = acc[2][fm][fn][r] + bni;
                float hn = bnh, hprev = 0.f;
                if (HAS_H) { hn += acc[3][fm][fn][r]; hprev = Hf[(size_t)i*Hh_ + j]; }
                const float rg = sigmoidf_(xr);
                const float zg = sigmoidf_(xz);
                const float ng = tanhf(xn + rg * hn);
                const float hp = (1.f - zg) * ng + zg * hprev;
                if (HAS_H) {
                    emb_b[(size_t)i*H_ + j] = f2bf(0.5f * (hprev + hp));
                } else {
                    Hout_f[(size_t)i*Hh_ + j] = hp;
                    Hout_b[(size_t)i*Hh_ + j] = f2bf(hp);
                }
            }
        }
    }
}

// ---------------------------------------------------------------------------
// block reductions
// ---------------------------------------------------------------------------
template<int NT>
__device__ __forceinline__ float block_reduce_max(float v, float* red) {
#pragma unroll
    for (int o = 32; o > 0; o >>= 1) v = fmaxf(v, __shfl_down(v, o));
    const int wid = threadIdx.x >> 6;
    if ((threadIdx.x & 63) == 0) red[wid] = v;
    __syncthreads();
    if (threadIdx.x == 0) {
        float m = red[0];
#pragma unroll
        for (int i = 1; i < NT/64; ++i) m = fmaxf(m, red[i]);
        red[0] = m;
    }
    __syncthreads();
    const float r = red[0];
    __syncthreads();
    return r;
}

template<int NT>
__device__ __forceinline__ float block_reduce_sum(float v, float* red) {
#pragma unroll
    for (int o = 32; o > 0; o >>= 1) v += __shfl_down(v, o);
    const int wid = threadIdx.x >> 6;
    if ((threadIdx.x & 63) == 0) red[wid] = v;
    __syncthreads();
    if (threadIdx.x == 0) {
        float m = red[0];
#pragma unroll
        for (int i = 1; i < NT/64; ++i) m += red[i];
        red[0] = m;
    }
    __syncthreads();
    const float r = red[0];
    __syncthreads();
    return r;
}

// ---------------------------------------------------------------------------
// attention per t. 512 threads. db in bf16.
// ---------------------------------------------------------------------------
__global__ __launch_bounds__(512) void attn_kernel(
    const ushort* __restrict__ db, const float* __restrict__ key,
    const int* __restrict__ attn_mask, float* __restrict__ attn)
{
    __shared__ float sk[H_];
    __shared__ float sl[U_];
    __shared__ float red[8];
    const int t = blockIdx.x;
    const int tid = threadIdx.x;

    if (tid < H_) sk[tid] = key[t*H_ + tid];
    __syncthreads();

#pragma unroll
    for (int uu = 0; uu < U_/512; ++uu) {
        const int u = tid + uu*512;
        const ushort* row = db + ((size_t)t*U_ + u)*H_;
        float s = 0.f;
        for (int k = 0; k < H_; ++k) s = fmaf(sk[k], bf2f(row[k]), s);
        sl[u] = attn_mask[t*U_ + u] ? s : -1e9f;
    }
    __syncthreads();

    float m = fmaxf(sl[tid], sl[tid + 512]);
    m = block_reduce_max<512>(m, red);

    const float e0 = expf(sl[tid] - m), e1 = expf(sl[tid+512] - m);
    sl[tid] = e0; sl[tid+512] = e1;
    float s = block_reduce_sum<512>(e0 + e1, red);
    const float inv = 1.f / s;
    __syncthreads();

    float a = 0.f;
    for (int u = 0; u < U_; ++u)
        a = fmaf(sl[u], bf2f(db[((size_t)t*U_ + u)*H_ + tid]), a);
    attn[t*H_ + tid] = a * inv;
}

// ---------------------------------------------------------------------------
// feature = finf + attn -> bf16
// ---------------------------------------------------------------------------
__global__ __launch_bounds__(256) void featcvt_kernel(
    const float* __restrict__ finf, const float* __restrict__ attn,
    ushort* __restrict__ featb)
{
    const int row = blockIdx.x;       // t*64+l
    const int t = row >> 6;
    const int h = threadIdx.x * 2;
    const float2 v = *(const float2*)(finf + (size_t)row*H_ + h);
    const float2 a = *(const float2*)(attn + t*H_ + h);
    ushort2 o; o.x = f2bf(v.x + a.x); o.y = f2bf(v.y + a.y);
    *(ushort2*)(featb + (size_t)row*H_ + h) = o;
}

// ---------------------------------------------------------------------------
// ff = tanh(featb @ Wb^T + bb) -> bf16.  M=1024, N=512, K=512.
// BM2=128, BN2=64, 4 waves 2x2.
// ---------------------------------------------------------------------------
__global__ __launch_bounds__(256) void ffgemm_kernel(
    const ushort* __restrict__ featb, const ushort* __restrict__ Wbb,
    const float* __restrict__ bb, ushort* __restrict__ ffb)
{
    __shared__ __align__(16) ushort As[128][BK];  // 16 KB
    __shared__ __align__(16) ushort Bs[64][BK];   // 8 KB

    const int tid = threadIdx.x;
    const int lane = tid & 63, wid = tid >> 6;
    const int wm = wid >> 1, wn = wid & 1;
    const int i0 = blockIdx.y * 128;
    const int j0 = blockIdx.x * 64;

    f32x4 acc[4][2] = {};

    for (int k0 = 0; k0 < H_; k0 += BK) {
#pragma unroll
        for (int cc = wid; cc < 24; cc += 4) {
            if (cc < 16) {
                const ushort* g = featb + (size_t)(i0 + cc*8 + (lane>>3))*H_ + k0 + (lane&7)*8;
                gload16(g, &As[0][0] + cc*512);
            } else {
                const int c = cc - 16;
                const ushort* g = Wbb + (size_t)(j0 + c*8 + (lane>>3))*H_ + k0 + (lane&7)*8;
                gload16(g, &Bs[0][0] + c*512);
            }
        }
        __syncthreads();
#pragma unroll
        for (int s = 0; s < 2; ++s) {
            bf16x8 af[4];
#pragma unroll
            for (int fm = 0; fm < 4; ++fm)
                af[fm] = *(const bf16x8*)&As[wm*64 + fm*16 + (lane&15)][s*32 + (lane>>4)*8];
#pragma unroll
            for (int fn = 0; fn < 2; ++fn) {
                const bf16x8 bv = *(const bf16x8*)&Bs[wn*32 + fn*16 + (lane&15)][s*32 + (lane>>4)*8];
#pragma unroll
                for (int fm = 0; fm < 4; ++fm)
                    acc[fm][fn] = __builtin_amdgcn_mfma_f32_16x16x32_bf16(
                        af[fm], bv, acc[fm][fn], 0, 0, 0);
            }
        }
        __syncthreads();
    }

#pragma unroll
    for (int fn = 0; fn < 2; ++fn) {
        const int j = j0 + wn*32 + fn*16 + (lane & 15);
        const float b = bb[j];
#pragma unroll
        for (int fm = 0; fm < 4; ++fm)
#pragma unroll
            for (int r = 0; r < 4; ++r) {
                const int i = i0 + wm*64 + fm*16 + (lane >> 4)*4 + r;
                ffb[(size_t)i*H_ + j] = f2bf(tanhf(acc[fm][fn][r] + b));
            }
    }
}

// ---------------------------------------------------------------------------
// logits[t*64+l, n] = ff[t*64+l,:] . V[n,:],  V = db_t rows (bx<16) or Kemb (bx==16)
// tile M=64, N=64, K=512. 4 waves, each 16 rows x 64 cols.
// ---------------------------------------------------------------------------
__global__ __launch_bounds__(256) void logits_kernel(
    const ushort* __restrict__ ffb, const ushort* __restrict__ dbb,
    const ushort* __restrict__ Kembb, float* __restrict__ logits)
{
    __shared__ __align__(16) ushort As[64][BK];   // 8 KB
    __shared__ __align__(16) ushort Bs[64][BK];   // 8 KB

    const int tid = threadIdx.x;
    const int lane = tid & 63, wid = tid >> 6;
    const int t = blockIdx.y;
    const int bx = blockIdx.x;
    const bool kw = (bx == 16);

    f32x4 acc[4] = {};

    for (int k0 = 0; k0 < H_; k0 += BK) {
#pragma unroll
        for (int cc = wid; cc < 16; cc += 4) {
            if (cc < 8) {
                const ushort* g = ffb + (size_t)(t*64 + cc*8 + (lane>>3))*H_ + k0 + (lane&7)*8;
                gload16(g, &As[0][0] + cc*512);
            } else {
                const int rloc = (cc-8)*8 + (lane>>3);
                const ushort* g = kw ? (Kembb + (size_t)rloc*H_ + k0 + (lane&7)*8)
                                     : (dbb + (size_t)(t*U_ + bx*64 + rloc)*H_ + k0 + (lane&7)*8);
                gload16(g, &Bs[0][0] + (cc-8)*512);
            }
        }
        __syncthreads();
#pragma unroll
        for (int s = 0; s < 2; ++s) {
            const bf16x8 af = *(const bf16x8*)&As[wid*16 + (lane&15)][s*32 + (lane>>4)*8];
#pragma unroll
            for (int fn = 0; fn < 4; ++fn) {
                const bf16x8 bv = *(const bf16x8*)&Bs[fn*16 + (lane&15)][s*32 + (lane>>4)*8];
                acc[fn] = __builtin_amdgcn_mfma_f32_16x16x32_bf16(af, bv, acc[fn], 0, 0, 0);
            }
        }
        __syncthreads();
    }

    const int ncols = U_ + K_;
#pragma unroll
    for (int fn = 0; fn < 4; ++fn) {
        const int jg = (kw ? U_ : bx*64) + fn*16 + (lane & 15);
#pragma unroll
        for (int r = 0; r < 4; ++r) {
            const int i = t*64 + wid*16 + (lane >> 4)*4 + r;
            logits[(size_t)i*ncols + jg] = acc[fn][r];
        }
    }
}

// ---------------------------------------------------------------------------
// per-row log_softmax over 1088 logits
// ---------------------------------------------------------------------------
__global__ __launch_bounds__(256) void lsm_kernel(
    const float* __restrict__ logits, float* __restrict__ out)
{
    __shared__ float sl[U_ + K_];
    __shared__ float red[4];
    const int row = blockIdx.x;
    const int tid = threadIdx.x;
    const int ncols = U_ + K_;

    float m = -3.4e38f;
    for (int idx = tid; idx < ncols; idx += 256) {
        const float v = logits[(size_t)row*ncols + idx];
        sl[idx] = v;
        m = fmaxf(m, v);
    }
    __syncthreads();
    m = block_reduce_max<256>(m, red);

    float s = 0.f;
    for (int idx = tid; idx < ncols; idx += 256) s += expf(sl[idx] - m);
    s = block_reduce_sum<256>(s, red);
    const float lse = m + logf(s);

    for (int idx = tid; idx < ncols; idx += 256)
        out[(size_t)row*ncols + idx] = sl[idx] - lse;
}

// ---------------------------------------------------------------------------
extern "C" void kernel_launch(void* const* d_in, const int* in_sizes, int n_in,
                              void* d_out, int out_size, void* d_ws, size_t ws_size,
                              hipStream_t stream)
{
    const float* feat  = (const float*)d_in[0];
    const float* key   = (const float*)d_in[1];
    const float* finf  = (const float*)d_in[2];
    const float* Wih_f = (const float*)d_in[3];
    const float* Whh_f = (const float*)d_in[4];
    const float* bih_f = (const float*)d_in[5];
    const float* bhh_f = (const float*)d_in[6];
    const float* Wih_b = (const float*)d_in[7];
    const float* Whh_b = (const float*)d_in[8];
    const float* bih_b = (const float*)d_in[9];
    const float* bhh_b = (const float*)d_in[10];
    const float* Wb    = (const float*)d_in[11];
    const float* bb    = (const float*)d_in[12];
    const float* Kemb  = (const float*)d_in[13];
    const int* col_idx  = (const int*)d_in[14];
    const int* col_mask = (const int*)d_in[15];
    const int* tab_idx  = (const int*)d_in[16];
    const int* tab_mask = (const int*)d_in[17];
    const int* attn_mask= (const int*)d_in[18];
    float* out = (float*)d_out;

    char* p = (char*)d_ws;
    ushort* wbf  = (ushort*)p;  p += (size_t)(2*(S0_+S1_) + WB_ + KE_)*2;  // 2.95 MB
    ushort* x1b  = (ushort*)p;  p += (size_t)M_*H_*2;                      // 16.8 MB
    ushort* x2b  = (ushort*)p;  p += (size_t)M_*H_*2;
    float*  f1f  = (float*)p;   p += (size_t)M_*Hh_*4;
    ushort* f1b  = (ushort*)p;  p += (size_t)M_*Hh_*2;
    float*  b1f  = (float*)p;   p += (size_t)M_*Hh_*4;
    ushort* b1b  = (ushort*)p;  p += (size_t)M_*Hh_*2;
    ushort* dbb  = (ushort*)p;  p += (size_t)M_*H_*2;                      // 16.8 MB
    float*  attn = (float*)p;   p += (size_t)T_*H_*4;
    ushort* featb= (ushort*)p;  p += (size_t)T_*L_*H_*2;
    ushort* ffb  = (ushort*)p;  p += (size_t)T_*L_*H_*2;
    float*  lg   = (float*)p;   p += (size_t)T_*L_*(U_+K_)*4;              // 4.45 MB

    const ushort* Wihf_b = wbf;
    const ushort* Whhf_b = wbf + S0_;
    const ushort* Wihb_b = wbf + S0_ + S1_;
    const ushort* Whhb_b = wbf + 2*S0_ + S1_;
    const ushort* Wbb    = wbf + 2*(S0_ + S1_);
    const ushort* Kembb  = wbf + 2*(S0_ + S1_) + WB_;

    wcvt_kernel<<<(2*(S0_+S1_) + WB_ + KE_)/1024, 256, 0, stream>>>(
        Wih_f, Whh_f, Wih_b, Whh_b, Wb, Kemb, wbf);

    meanpool_kernel<<<dim3(U_, T_), 256, 0, stream>>>(
        feat, col_idx, col_mask, tab_idx, tab_mask, x1b, x2b);

    dim3 gg(Hh_/BNG, M_/BM);   // (4, 128)
    gru_mfma_kernel<false><<<gg, 256, 0, stream>>>(x1b, nullptr, nullptr, Wihf_b, Whhf_b,
                                                   bih_f, bhh_f, f1f, f1b, nullptr);
    gru_mfma_kernel<false><<<gg, 256, 0, stream>>>(x2b, nullptr, nullptr, Wihb_b, Whhb_b,
                                                   bih_b, bhh_b, b1f, b1b, nullptr);
    gru_mfma_kernel<true ><<<gg, 256, 0, stream>>>(x2b, f1b, f1f, Wihf_b, Whhf_b,
                                                   bih_f, bhh_f, nullptr, nullptr, dbb);
    gru_mfma_kernel<true ><<<gg, 256, 0, stream>>>(x1b, b1b, b1f, Wihb_b, Whhb_b,
                                                   bih_b, bhh_b, nullptr, nullptr, dbb + Hh_);

    attn_kernel<<<T_, 512, 0, stream>>>(dbb, key, attn_mask, attn);
    featcvt_kernel<<<T_*L_, 256, 0, stream>>>(finf, attn, featb);
    ffgemm_kernel<<<dim3(H_/64, (T_*L_)/128), 256, 0, stream>>>(featb, Wbb, bb, ffb);
    logits_kernel<<<dim3(17, T_), 256, 0, stream>>>(ffb, dbb, Kembb, lg);
    lsm_kernel<<<T_*L_, 256, 0, stream>>>(lg, out);
}

// Round 4
// 389.689 us; speedup vs baseline: 3.9099x; 1.1867x over previous
//
#include <hip/hip_runtime.h>
#include <math.h>

#define T_  16
#define DB2_ 512
#define H_  512
#define Hh_ 256
#define U_  1024
#define MC_ 8
#define MT_ 4
#define L_  64
#define K_  64
#define M_  (T_*U_)   // 16384

#define BM 128
#define BNG 64
#define BK 64
#define S0_ (768*512)
#define S1_ (768*256)
#define WB_ (512*512)
#define KE_ (64*512)

typedef __attribute__((ext_vector_type(8))) short bf16x8;
typedef __attribute__((ext_vector_type(4))) float f32x4;

__device__ __forceinline__ float sigmoidf_(float x) { return 1.f / (1.f + expf(-x)); }

__device__ __forceinline__ ushort f2bf(float f) {
    union { float f; unsigned u; } v; v.f = f;
    const unsigned r = (v.u + 0x7FFFu + ((v.u >> 16) & 1u)) >> 16;
    return (ushort)r;
}
__device__ __forceinline__ float bf2f(ushort u) {
    union { unsigned u; float f; } v; v.u = ((unsigned)u) << 16; return v.f;
}

__device__ __forceinline__ void gload16(const void* g, void* l) {
    __builtin_amdgcn_global_load_lds(
        (const __attribute__((address_space(1))) void*)g,
        (__attribute__((address_space(3))) void*)l, 16, 0, 0);
}

// ---------------------------------------------------------------------------
// Kernel 0: convert weights to bf16: Wih_f|Whh_f|Wih_b|Whh_b|Wb|Kemb
// ---------------------------------------------------------------------------
__global__ __launch_bounds__(256) void wcvt_kernel(
    const float* __restrict__ w0, const float* __restrict__ w1,
    const float* __restrict__ w2, const float* __restrict__ w3,
    const float* __restrict__ w4, const float* __restrict__ w5,
    ushort* __restrict__ dst)
{
    const int idx = (blockIdx.x * 256 + threadIdx.x) * 4;
    const float* src; int local;
    if      (idx < S0_)                  { src = w0; local = idx; }
    else if (idx < S0_ + S1_)            { src = w1; local = idx - S0_; }
    else if (idx < 2*S0_ + S1_)          { src = w2; local = idx - S0_ - S1_; }
    else if (idx < 2*S0_ + 2*S1_)        { src = w3; local = idx - 2*S0_ - S1_; }
    else if (idx < 2*S0_ + 2*S1_ + WB_)  { src = w4; local = idx - 2*S0_ - 2*S1_; }
    else                                 { src = w5; local = idx - 2*S0_ - 2*S1_ - WB_; }
    const float4 v = *(const float4*)(src + local);
    ushort4 o; o.x = f2bf(v.x); o.y = f2bf(v.y); o.z = f2bf(v.z); o.w = f2bf(v.w);
    *(ushort4*)(dst + idx) = o;
}

// ---------------------------------------------------------------------------
// Kernel 1: masked mean pooling -> x1 (tab), x2 (col) in bf16
// ---------------------------------------------------------------------------
__global__ __launch_bounds__(256) void meanpool_kernel(
    const float* __restrict__ feat,
    const int* __restrict__ col_idx, const int* __restrict__ col_mask,
    const int* __restrict__ tab_idx, const int* __restrict__ tab_mask,
    ushort* __restrict__ x1, ushort* __restrict__ x2)
{
    const int u = blockIdx.x;
    const int t = blockIdx.y;
    const int tid = threadIdx.x;

    int ci[MC_], cm[MC_], ti[MT_], tm[MT_];
    float cc = 0.f, tc = 0.f;
#pragma unroll
    for (int m = 0; m < MC_; ++m) { ci[m] = col_idx[u*MC_+m]; cm[m] = col_mask[u*MC_+m]; cc += (float)cm[m]; }
#pragma unroll
    for (int m = 0; m < MT_; ++m) { ti[m] = tab_idx[u*MT_+m]; tm[m] = tab_mask[u*MT_+m]; tc += (float)tm[m]; }
    const float rc = 1.f / fmaxf(cc, 1.f);
    const float rt = 1.f / fmaxf(tc, 1.f);

    const float* fb = feat + (size_t)t * DB2_ * H_;
    const int h = tid * 2;

    float acx = 0.f, acy = 0.f, atx = 0.f, aty = 0.f;
#pragma unroll
    for (int m = 0; m < MC_; ++m) if (cm[m]) {
        const float2 v = *(const float2*)(fb + (size_t)ci[m]*H_ + h);
        acx += v.x; acy += v.y;
    }
#pragma unroll
    for (int m = 0; m < MT_; ++m) if (tm[m]) {
        const float2 v = *(const float2*)(fb + (size_t)ti[m]*H_ + h);
        atx += v.x; aty += v.y;
    }
    const size_t o = ((size_t)(t*U_ + u))*H_ + h;
    ushort2 c2; c2.x = f2bf(acx*rc); c2.y = f2bf(acy*rc);
    ushort2 t2; t2.x = f2bf(atx*rt); t2.y = f2bf(aty*rt);
    *(ushort2*)(x2 + o) = c2;
    *(ushort2*)(x1 + o) = t2;
}

// ---------------------------------------------------------------------------
// GRU cells via MFMA, swizzled LDS.  blockIdx.z selects {fwd, bwd} params.
// Swizzle: LDS slot (row, col16) holds global col16 ^ (row&7); gload_lds dest
// stays linear (write row&7 == lane>>3, read row&7 == lane&7).
// ---------------------------------------------------------------------------
__device__ __forceinline__ void stage_tiles(
    const ushort* __restrict__ Xb, int ldx,
    const ushort* __restrict__ Wb, int ldw,
    int i0, int j0, int k0,
    ushort* AsBase, ushort* BsBase, int lane, int wid)
{
    const int csw  = (((lane & 7) ^ (lane >> 3)) * 8);   // swizzled source col (ushorts)
    const int rsub = lane >> 3;
#pragma unroll
    for (int cc = wid; cc < 40; cc += 4) {
        if (cc < 16) {
            const ushort* g = Xb + (size_t)(i0 + cc*8 + rsub)*ldx + k0 + csw;
            gload16(g, AsBase + cc*512);
        } else {
            const int c = cc - 16;
            const int rowB = c*8 + rsub;
            const ushort* g = Wb + (size_t)((rowB>>6)*Hh_ + j0 + (rowB&63))*ldw + k0 + csw;
            gload16(g, BsBase + c*512);
        }
    }
}

template<int GN>
__device__ __forceinline__ void compute_tile(
    f32x4 (&acc)[4][4][2],
    const ushort (&As)[BM][BK], const ushort (&Bs)[192][BK],
    int lane, int wm, int wn)
{
#pragma unroll
    for (int s = 0; s < 2; ++s) {
        const int colr = (((s*4 + (lane>>4)) ^ (lane & 7)) * 8);  // swizzled read col
        bf16x8 af[4];
#pragma unroll
        for (int fm = 0; fm < 4; ++fm)
            af[fm] = *(const bf16x8*)&As[wm*64 + fm*16 + (lane&15)][colr];
#pragma unroll
        for (int g = 0; g < 3; ++g) {
            const int gi = (g == 2) ? GN : g;
#pragma unroll
            for (int fn = 0; fn < 2; ++fn) {
                const bf16x8 bv = *(const bf16x8*)&Bs[g*64 + wn*32 + fn*16 + (lane&15)][colr];
#pragma unroll
                for (int fm = 0; fm < 4; ++fm)
                    acc[gi][fm][fn] = __builtin_amdgcn_mfma_f32_16x16x32_bf16(
                        af[fm], bv, acc[gi][fm][fn], 0, 0, 0);
            }
        }
    }
}

template<bool HAS_H>
__global__ __launch_bounds__(256) void gru2_kernel(
    const ushort* __restrict__ X0, const ushort* __restrict__ X1,
    const ushort* __restrict__ Hb0, const ushort* __restrict__ Hb1,
    const float*  __restrict__ Hf0, const float*  __restrict__ Hf1,
    const ushort* __restrict__ Wih0, const ushort* __restrict__ Wih1,
    const ushort* __restrict__ Whh0, const ushort* __restrict__ Whh1,
    const float* __restrict__ bih0, const float* __restrict__ bih1,
    const float* __restrict__ bhh0, const float* __restrict__ bhh1,
    float* __restrict__ HoutF0, float* __restrict__ HoutF1,
    ushort* __restrict__ HoutB0, ushort* __restrict__ HoutB1,
    ushort* __restrict__ emb0, ushort* __restrict__ emb1)
{
    __shared__ __align__(16) ushort As[BM][BK];   // 16 KB
    __shared__ __align__(16) ushort Bs[192][BK];  // 24 KB

    const int sel = blockIdx.z;
    const ushort* Xb   = sel ? X1 : X0;
    const ushort* Hb   = sel ? Hb1 : Hb0;
    const float*  Hf   = sel ? Hf1 : Hf0;
    const ushort* Wihb = sel ? Wih1 : Wih0;
    const ushort* Whhb = sel ? Whh1 : Whh0;
    const float*  bih  = sel ? bih1 : bih0;
    const float*  bhh  = sel ? bhh1 : bhh0;
    float*  Hout_f = sel ? HoutF1 : HoutF0;
    ushort* Hout_b = sel ? HoutB1 : HoutB0;
    ushort* emb_b  = sel ? emb1 : emb0;

    const int tid = threadIdx.x;
    const int lane = tid & 63, wid = tid >> 6;
    const int wm = wid >> 1, wn = wid & 1;
    const int i0 = blockIdx.y * BM;
    const int j0 = blockIdx.x * BNG;

    f32x4 acc[4][4][2] = {};   // [r,z,n_ih | n_hh][fm][fn]

    for (int k0 = 0; k0 < H_; k0 += BK) {
        stage_tiles(Xb, H_, Wihb, H_, i0, j0, k0, &As[0][0], &Bs[0][0], lane, wid);
        __syncthreads();
        compute_tile<2>(acc, As, Bs, lane, wm, wn);
        __syncthreads();
    }
    if (HAS_H) {
        for (int k0 = 0; k0 < Hh_; k0 += BK) {
            stage_tiles(Hb, Hh_, Whhb, Hh_, i0, j0, k0, &As[0][0], &Bs[0][0], lane, wid);
            __syncthreads();
            compute_tile<3>(acc, As, Bs, lane, wm, wn);
            __syncthreads();
        }
    }

#pragma unroll
    for (int fn = 0; fn < 2; ++fn) {
        const int j = j0 + wn*32 + fn*16 + (lane & 15);
        const float bri = bih[j],       brh = bhh[j];
        const float bzi = bih[Hh_ + j], bzh = bhh[Hh_ + j];
        const float bni = bih[2*Hh_+j], bnh = bhh[2*Hh_ + j];
#pragma unroll
        for (int fm = 0; fm < 4; ++fm) {
#pragma unroll
            for (int r = 0; r < 4; ++r) {
                const int i = i0 + wm*64 + fm*16 + (lane >> 4)*4 + r;
                const float xr = acc[0][fm][fn][r] + bri + brh;
                const float xz = acc[1][fm][fn][r] + bzi + bzh;
                const float xn = acc[2][fm][fn][r] + bni;
                float hn = bnh, hprev = 0.f;
                if (HAS_H) { hn += acc[3][fm][fn][r]; hprev = Hf[(size_t)i*Hh_ + j]; }
                const float rg = sigmoidf_(xr);
                const float zg = sigmoidf_(xz);
                const float ng = tanhf(xn + rg * hn);
                const float hp = (1.f - zg) * ng + zg * hprev;
                if (HAS_H) {
                    emb_b[(size_t)i*H_ + j] = f2bf(0.5f * (hprev + hp));
                } else {
                    Hout_f[(size_t)i*Hh_ + j] = hp;
                    Hout_b[(size_t)i*Hh_ + j] = f2bf(hp);
                }
            }
        }
    }
}

// ---------------------------------------------------------------------------
// block reductions
// ---------------------------------------------------------------------------
template<int NT>
__device__ __forceinline__ float block_reduce_max(float v, float* red) {
#pragma unroll
    for (int o = 32; o > 0; o >>= 1) v = fmaxf(v, __shfl_down(v, o));
    const int wid = threadIdx.x >> 6;
    if ((threadIdx.x & 63) == 0) red[wid] = v;
    __syncthreads();
    if (threadIdx.x == 0) {
        float m = red[0];
#pragma unroll
        for (int i = 1; i < NT/64; ++i) m = fmaxf(m, red[i]);
        red[0] = m;
    }
    __syncthreads();
    const float r = red[0];
    __syncthreads();
    return r;
}

template<int NT>
__device__ __forceinline__ float block_reduce_sum(float v, float* red) {
#pragma unroll
    for (int o = 32; o > 0; o >>= 1) v += __shfl_down(v, o);
    const int wid = threadIdx.x >> 6;
    if ((threadIdx.x & 63) == 0) red[wid] = v;
    __syncthreads();
    if (threadIdx.x == 0) {
        float m = red[0];
#pragma unroll
        for (int i = 1; i < NT/64; ++i) m += red[i];
        red[0] = m;
    }
    __syncthreads();
    const float r = red[0];
    __syncthreads();
    return r;
}

// ---------------------------------------------------------------------------
// attention, split for parallelism.
// A: logits.  grid (16, T), 256 threads: 64 u/block, 4 threads per u.
// ---------------------------------------------------------------------------
__global__ __launch_bounds__(256) void attn_logits_kernel(
    const ushort* __restrict__ db, const float* __restrict__ key,
    const int* __restrict__ attn_mask, float* __restrict__ alog)
{
    const int t = blockIdx.y;
    const int tid = threadIdx.x;
    const int u = blockIdx.x*64 + (tid >> 2);
    const int kq = (tid & 3) * 128;

    const bf16x8* r8 = (const bf16x8*)(db + ((size_t)t*U_ + u)*H_ + kq);
    const float* kp = key + t*H_ + kq;
    float s = 0.f;
#pragma unroll
    for (int k8 = 0; k8 < 16; ++k8) {
        const bf16x8 v = r8[k8];
#pragma unroll
        for (int j = 0; j < 8; ++j)
            s = fmaf(kp[k8*8 + j], bf2f((ushort)v[j]), s);
    }
    s += __shfl_xor(s, 1);
    s += __shfl_xor(s, 2);
    if ((tid & 3) == 0)
        alog[t*U_ + u] = attn_mask[t*U_ + u] ? s : -1e9f;
}

// B: softmax -> weights. grid T, 512 threads.
__global__ __launch_bounds__(512) void attn_softmax_kernel(
    const float* __restrict__ alog, float* __restrict__ aw)
{
    __shared__ float red[8];
    const int t = blockIdx.x, tid = threadIdx.x;
    const float v0 = alog[t*U_ + tid], v1 = alog[t*U_ + tid + 512];
    const float m = block_reduce_max<512>(fmaxf(v0, v1), red);
    const float e0 = expf(v0 - m), e1 = expf(v1 - m);
    const float s = block_reduce_sum<512>(e0 + e1, red);
    const float inv = 1.f / s;
    aw[t*U_ + tid] = e0 * inv;
    aw[t*U_ + tid + 512] = e1 * inv;
}

// C: weighted sum partials. grid (8, T), 512 threads: 128 u per block.
__global__ __launch_bounds__(512) void attn_wsum_kernel(
    const ushort* __restrict__ db, const float* __restrict__ aw,
    float* __restrict__ part)
{
    const int t = blockIdx.y, u0 = blockIdx.x * 128;
    const int h = threadIdx.x;
    float a = 0.f;
    for (int u = 0; u < 128; ++u)
        a = fmaf(aw[t*U_ + u0 + u], bf2f(db[((size_t)t*U_ + u0 + u)*H_ + h]), a);
    part[((size_t)blockIdx.x*T_ + t)*H_ + h] = a;
}

// ---------------------------------------------------------------------------
// feature = finf + sum(part) -> bf16
// ---------------------------------------------------------------------------
__global__ __launch_bounds__(256) void featcvt_kernel(
    const float* __restrict__ finf, const float* __restrict__ part,
    ushort* __restrict__ featb)
{
    const int row = blockIdx.x;       // t*64+l
    const int t = row >> 6;
    const int h = threadIdx.x * 2;
    const float2 v = *(const float2*)(finf + (size_t)row*H_ + h);
    float ax = 0.f, ay = 0.f;
#pragma unroll
    for (int p = 0; p < 8; ++p) {
        const float2 a = *(const float2*)(part + ((size_t)p*T_ + t)*H_ + h);
        ax += a.x; ay += a.y;
    }
    ushort2 o; o.x = f2bf(v.x + ax); o.y = f2bf(v.y + ay);
    *(ushort2*)(featb + (size_t)row*H_ + h) = o;
}

// ---------------------------------------------------------------------------
// ff = tanh(featb @ Wb^T + bb) -> bf16.  M=1024, N=512, K=512. Swizzled LDS.
// ---------------------------------------------------------------------------
__global__ __launch_bounds__(256) void ffgemm_kernel(
    const ushort* __restrict__ featb, const ushort* __restrict__ Wbb,
    const float* __restrict__ bb, ushort* __restrict__ ffb)
{
    __shared__ __align__(16) ushort As[128][BK];  // 16 KB
    __shared__ __align__(16) ushort Bs[64][BK];   // 8 KB

    const int tid = threadIdx.x;
    const int lane = tid & 63, wid = tid >> 6;
    const int wm = wid >> 1, wn = wid & 1;
    const int i0 = blockIdx.y * 128;
    const int j0 = blockIdx.x * 64;
    const int csw  = (((lane & 7) ^ (lane >> 3)) * 8);
    const int rsub = lane >> 3;

    f32x4 acc[4][2] = {};

    for (int k0 = 0; k0 < H_; k0 += BK) {
#pragma unroll
        for (int cc = wid; cc < 24; cc += 4) {
            if (cc < 16) {
                const ushort* g = featb + (size_t)(i0 + cc*8 + rsub)*H_ + k0 + csw;
                gload16(g, &As[0][0] + cc*512);
            } else {
                const int c = cc - 16;
                const ushort* g = Wbb + (size_t)(j0 + c*8 + rsub)*H_ + k0 + csw;
                gload16(g, &Bs[0][0] + c*512);
            }
        }
        __syncthreads();
#pragma unroll
        for (int s = 0; s < 2; ++s) {
            const int colr = (((s*4 + (lane>>4)) ^ (lane & 7)) * 8);
            bf16x8 af[4];
#pragma unroll
            for (int fm = 0; fm < 4; ++fm)
                af[fm] = *(const bf16x8*)&As[wm*64 + fm*16 + (lane&15)][colr];
#pragma unroll
            for (int fn = 0; fn < 2; ++fn) {
                const bf16x8 bv = *(const bf16x8*)&Bs[wn*32 + fn*16 + (lane&15)][colr];
#pragma unroll
                for (int fm = 0; fm < 4; ++fm)
                    acc[fm][fn] = __builtin_amdgcn_mfma_f32_16x16x32_bf16(
                        af[fm], bv, acc[fm][fn], 0, 0, 0);
            }
        }
        __syncthreads();
    }

#pragma unroll
    for (int fn = 0; fn < 2; ++fn) {
        const int j = j0 + wn*32 + fn*16 + (lane & 15);
        const float b = bb[j];
#pragma unroll
        for (int fm = 0; fm < 4; ++fm)
#pragma unroll
            for (int r = 0; r < 4; ++r) {
                const int i = i0 + wm*64 + fm*16 + (lane >> 4)*4 + r;
                ffb[(size_t)i*H_ + j] = f2bf(tanhf(acc[fm][fn][r] + b));
            }
    }
}

// ---------------------------------------------------------------------------
// logits[t*64+l, n] = ff[t*64+l,:] . V[n,:].  Swizzled LDS.
// ---------------------------------------------------------------------------
__global__ __launch_bounds__(256) void logits_kernel(
    const ushort* __restrict__ ffb, const ushort* __restrict__ dbb,
    const ushort* __restrict__ Kembb, float* __restrict__ logits)
{
    __shared__ __align__(16) ushort As[64][BK];   // 8 KB
    __shared__ __align__(16) ushort Bs[64][BK];   // 8 KB

    const int tid = threadIdx.x;
    const int lane = tid & 63, wid = tid >> 6;
    const int t = blockIdx.y;
    const int bx = blockIdx.x;
    const bool kw = (bx == 16);
    const int csw  = (((lane & 7) ^ (lane >> 3)) * 8);
    const int rsub = lane >> 3;

    f32x4 acc[4] = {};

    for (int k0 = 0; k0 < H_; k0 += BK) {
#pragma unroll
        for (int cc = wid; cc < 16; cc += 4) {
            if (cc < 8) {
                const ushort* g = ffb + (size_t)(t*64 + cc*8 + rsub)*H_ + k0 + csw;
                gload16(g, &As[0][0] + cc*512);
            } else {
                const int rloc = (cc-8)*8 + rsub;
                const ushort* g = kw ? (Kembb + (size_t)rloc*H_ + k0 + csw)
                                     : (dbb + (size_t)(t*U_ + bx*64 + rloc)*H_ + k0 + csw);
                gload16(g, &Bs[0][0] + (cc-8)*512);
            }
        }
        __syncthreads();
#pragma unroll
        for (int s = 0; s < 2; ++s) {
            const int colr = (((s*4 + (lane>>4)) ^ (lane & 7)) * 8);
            const bf16x8 af = *(const bf16x8*)&As[wid*16 + (lane&15)][colr];
#pragma unroll
            for (int fn = 0; fn < 4; ++fn) {
                const bf16x8 bv = *(const bf16x8*)&Bs[fn*16 + (lane&15)][colr];
                acc[fn] = __builtin_amdgcn_mfma_f32_16x16x32_bf16(af, bv, acc[fn], 0, 0, 0);
            }
        }
        __syncthreads();
    }

    const int ncols = U_ + K_;
#pragma unroll
    for (int fn = 0; fn < 4; ++fn) {
        const int jg = (kw ? U_ : bx*64) + fn*16 + (lane & 15);
#pragma unroll
        for (int r = 0; r < 4; ++r) {
            const int i = t*64 + wid*16 + (lane >> 4)*4 + r;
            logits[(size_t)i*ncols + jg] = acc[fn][r];
        }
    }
}

// ---------------------------------------------------------------------------
// per-row log_softmax over 1088 logits
// ---------------------------------------------------------------------------
__global__ __launch_bounds__(256) void lsm_kernel(
    const float* __restrict__ logits, float* __restrict__ out)
{
    __shared__ float sl[U_ + K_];
    __shared__ float red[4];
    const int row = blockIdx.x;
    const int tid = threadIdx.x;
    const int ncols = U_ + K_;

    float m = -3.4e38f;
    for (int idx = tid; idx < ncols; idx += 256) {
        const float v = logits[(size_t)row*ncols + idx];
        sl[idx] = v;
        m = fmaxf(m, v);
    }
    __syncthreads();
    m = block_reduce_max<256>(m, red);

    float s = 0.f;
    for (int idx = tid; idx < ncols; idx += 256) s += expf(sl[idx] - m);
    s = block_reduce_sum<256>(s, red);
    const float lse = m + logf(s);

    for (int idx = tid; idx < ncols; idx += 256)
        out[(size_t)row*ncols + idx] = sl[idx] - lse;
}

// ---------------------------------------------------------------------------
extern "C" void kernel_launch(void* const* d_in, const int* in_sizes, int n_in,
                              void* d_out, int out_size, void* d_ws, size_t ws_size,
                              hipStream_t stream)
{
    const float* feat  = (const float*)d_in[0];
    const float* key   = (const float*)d_in[1];
    const float* finf  = (const float*)d_in[2];
    const float* Wih_f = (const float*)d_in[3];
    const float* Whh_f = (const float*)d_in[4];
    const float* bih_f = (const float*)d_in[5];
    const float* bhh_f = (const float*)d_in[6];
    const float* Wih_b = (const float*)d_in[7];
    const float* Whh_b = (const float*)d_in[8];
    const float* bih_b = (const float*)d_in[9];
    const float* bhh_b = (const float*)d_in[10];
    const float* Wb    = (const float*)d_in[11];
    const float* bb    = (const float*)d_in[12];
    const float* Kemb  = (const float*)d_in[13];
    const int* col_idx  = (const int*)d_in[14];
    const int* col_mask = (const int*)d_in[15];
    const int* tab_idx  = (const int*)d_in[16];
    const int* tab_mask = (const int*)d_in[17];
    const int* attn_mask= (const int*)d_in[18];
    float* out = (float*)d_out;

    char* p = (char*)d_ws;
    ushort* wbf  = (ushort*)p;  p += (size_t)(2*(S0_+S1_) + WB_ + KE_)*2;  // 2.95 MB
    ushort* x1b  = (ushort*)p;  p += (size_t)M_*H_*2;                      // 16.8 MB
    ushort* x2b  = (ushort*)p;  p += (size_t)M_*H_*2;
    float*  f1f  = (float*)p;   p += (size_t)M_*Hh_*4;
    ushort* f1b  = (ushort*)p;  p += (size_t)M_*Hh_*2;
    float*  b1f  = (float*)p;   p += (size_t)M_*Hh_*4;
    ushort* b1b  = (ushort*)p;  p += (size_t)M_*Hh_*2;
    ushort* dbb  = (ushort*)p;  p += (size_t)M_*H_*2;                      // 16.8 MB
    float*  alog = (float*)p;   p += (size_t)T_*U_*4;
    float*  aw   = (float*)p;   p += (size_t)T_*U_*4;
    float*  part = (float*)p;   p += (size_t)8*T_*H_*4;
    ushort* featb= (ushort*)p;  p += (size_t)T_*L_*H_*2;
    ushort* ffb  = (ushort*)p;  p += (size_t)T_*L_*H_*2;
    float*  lg   = (float*)p;   p += (size_t)T_*L_*(U_+K_)*4;              // 4.45 MB

    const ushort* Wihf_b = wbf;
    const ushort* Whhf_b = wbf + S0_;
    const ushort* Wihb_b = wbf + S0_ + S1_;
    const ushort* Whhb_b = wbf + 2*S0_ + S1_;
    const ushort* Wbb    = wbf + 2*(S0_ + S1_);
    const ushort* Kembb  = wbf + 2*(S0_ + S1_) + WB_;

    wcvt_kernel<<<(2*(S0_+S1_) + WB_ + KE_)/1024, 256, 0, stream>>>(
        Wih_f, Whh_f, Wih_b, Whh_b, Wb, Kemb, wbf);

    meanpool_kernel<<<dim3(U_, T_), 256, 0, stream>>>(
        feat, col_idx, col_mask, tab_idx, tab_mask, x1b, x2b);

    dim3 gg(Hh_/BNG, M_/BM, 2);   // (4, 128, 2)
    gru2_kernel<false><<<gg, 256, 0, stream>>>(
        x1b, x2b, nullptr, nullptr, nullptr, nullptr,
        Wihf_b, Wihb_b, Whhf_b, Whhb_b, bih_f, bih_b, bhh_f, bhh_b,
        f1f, b1f, f1b, b1b, nullptr, nullptr);
    gru2_kernel<true><<<gg, 256, 0, stream>>>(
        x2b, x1b, f1b, b1b, f1f, b1f,
        Wihf_b, Wihb_b, Whhf_b, Whhb_b, bih_f, bih_b, bhh_f, bhh_b,
        nullptr, nullptr, nullptr, nullptr, dbb, dbb + Hh_);

    attn_logits_kernel<<<dim3(16, T_), 256, 0, stream>>>(dbb, key, attn_mask, alog);
    attn_softmax_kernel<<<T_, 512, 0, stream>>>(alog, aw);
    attn_wsum_kernel<<<dim3(8, T_), 512, 0, stream>>>(dbb, aw, part);
    featcvt_kernel<<<T_*L_, 256, 0, stream>>>(finf, part, featb);
    ffgemm_kernel<<<dim3(H_/64, (T_*L_)/128), 256, 0, stream>>>(featb, Wbb, bb, ffb);
    logits_kernel<<<dim3(17, T_), 256, 0, stream>>>(ffb, dbb, Kembb, lg);
    lsm_kernel<<<T_*L_, 256, 0, stream>>>(lg, out);
}

// Round 8
// 290.286 us; speedup vs baseline: 5.2488x; 1.3424x over previous
//
#include <hip/hip_runtime.h>
#include <math.h>

#define T_  16
#define DB2_ 512
#define H_  512
#define Hh_ 256
#define U_  1024
#define MC_ 8
#define MT_ 4
#define L_  64
#define K_  64
#define M_  (T_*U_)   // 16384

#define BM 64
#define BNG 64
#define BK 64
#define S0_ (768*512)
#define S1_ (768*256)
#define WB_ (512*512)
#define KE_ (64*512)

typedef __attribute__((ext_vector_type(8))) short bf16x8;
typedef __attribute__((ext_vector_type(4))) float f32x4;

__device__ __forceinline__ float sigmoidf_(float x) { return 1.f / (1.f + expf(-x)); }

__device__ __forceinline__ ushort f2bf(float f) {
    union { float f; unsigned u; } v; v.f = f;
    const unsigned r = (v.u + 0x7FFFu + ((v.u >> 16) & 1u)) >> 16;
    return (ushort)r;
}
__device__ __forceinline__ float bf2f(ushort u) {
    union { unsigned u; float f; } v; v.u = ((unsigned)u) << 16; return v.f;
}

__device__ __forceinline__ void gload16(const void* g, void* l) {
    __builtin_amdgcn_global_load_lds(
        (const __attribute__((address_space(1))) void*)g,
        (__attribute__((address_space(3))) void*)l, 16, 0, 0);
}

// ---------------------------------------------------------------------------
// Kernel 0: convert weights to bf16: Wih_f|Whh_f|Wih_b|Whh_b|Wb|Kemb
// ---------------------------------------------------------------------------
__global__ __launch_bounds__(256) void wcvt_kernel(
    const float* __restrict__ w0, const float* __restrict__ w1,
    const float* __restrict__ w2, const float* __restrict__ w3,
    const float* __restrict__ w4, const float* __restrict__ w5,
    ushort* __restrict__ dst)
{
    const int idx = (blockIdx.x * 256 + threadIdx.x) * 4;
    const float* src; int local;
    if      (idx < S0_)                  { src = w0; local = idx; }
    else if (idx < S0_ + S1_)            { src = w1; local = idx - S0_; }
    else if (idx < 2*S0_ + S1_)          { src = w2; local = idx - S0_ - S1_; }
    else if (idx < 2*S0_ + 2*S1_)        { src = w3; local = idx - 2*S0_ - S1_; }
    else if (idx < 2*S0_ + 2*S1_ + WB_)  { src = w4; local = idx - 2*S0_ - 2*S1_; }
    else                                 { src = w5; local = idx - 2*S0_ - 2*S1_ - WB_; }
    const float4 v = *(const float4*)(src + local);
    ushort4 o; o.x = f2bf(v.x); o.y = f2bf(v.y); o.z = f2bf(v.z); o.w = f2bf(v.w);
    *(ushort4*)(dst + idx) = o;
}

// ---------------------------------------------------------------------------
// Kernel 1: masked mean pooling -> x1 (tab), x2 (col) in bf16
// ---------------------------------------------------------------------------
__global__ __launch_bounds__(256) void meanpool_kernel(
    const float* __restrict__ feat,
    const int* __restrict__ col_idx, const int* __restrict__ col_mask,
    const int* __restrict__ tab_idx, const int* __restrict__ tab_mask,
    ushort* __restrict__ x1, ushort* __restrict__ x2)
{
    const int u = blockIdx.x;
    const int t = blockIdx.y;
    const int tid = threadIdx.x;

    int ci[MC_], cm[MC_], ti[MT_], tm[MT_];
    float cc = 0.f, tc = 0.f;
#pragma unroll
    for (int m = 0; m < MC_; ++m) { ci[m] = col_idx[u*MC_+m]; cm[m] = col_mask[u*MC_+m]; cc += (float)cm[m]; }
#pragma unroll
    for (int m = 0; m < MT_; ++m) { ti[m] = tab_idx[u*MT_+m]; tm[m] = tab_mask[u*MT_+m]; tc += (float)tm[m]; }
    const float rc = 1.f / fmaxf(cc, 1.f);
    const float rt = 1.f / fmaxf(tc, 1.f);

    const float* fb = feat + (size_t)t * DB2_ * H_;
    const int h = tid * 2;

    float acx = 0.f, acy = 0.f, atx = 0.f, aty = 0.f;
#pragma unroll
    for (int m = 0; m < MC_; ++m) if (cm[m]) {
        const float2 v = *(const float2*)(fb + (size_t)ci[m]*H_ + h);
        acx += v.x; acy += v.y;
    }
#pragma unroll
    for (int m = 0; m < MT_; ++m) if (tm[m]) {
        const float2 v = *(const float2*)(fb + (size_t)ti[m]*H_ + h);
        atx += v.x; aty += v.y;
    }
    const size_t o = ((size_t)(t*U_ + u))*H_ + h;
    ushort2 c2; c2.x = f2bf(acx*rc); c2.y = f2bf(acy*rc);
    ushort2 t2; t2.x = f2bf(atx*rt); t2.y = f2bf(aty*rt);
    *(ushort2*)(x2 + o) = c2;
    *(ushort2*)(x1 + o) = t2;
}

// ---------------------------------------------------------------------------
// GRU cells via MFMA, swizzled LDS.  BM=64, 4 waves of 32x32x3gates.
// acc = 64 regs/thread -> target 4 waves/SIMD (prev 128 regs -> 1 wave/SIMD).
// blockIdx.x is XCD-remapped: flat = ((i/8)*4 + j)*8 + i%8, so the 4 j-blocks
// sharing an X panel land on the same XCD's L2.
// ---------------------------------------------------------------------------
__device__ __forceinline__ void stage_tiles64(
    const ushort* __restrict__ Xb, int ldx,
    const ushort* __restrict__ Wb, int ldw,
    int i0, int j0, int k0,
    ushort* AsBase, ushort* BsBase, int lane, int wid)
{
    const int csw  = (((lane & 7) ^ (lane >> 3)) * 8);   // swizzled source col (ushorts)
    const int rsub = lane >> 3;
#pragma unroll
    for (int cc = wid; cc < 32; cc += 4) {
        if (cc < 8) {
            const ushort* g = Xb + (size_t)(i0 + cc*8 + rsub)*ldx + k0 + csw;
            gload16(g, AsBase + cc*512);
        } else {
            const int c = cc - 8;
            const int rowB = c*8 + rsub;
            const ushort* g = Wb + (size_t)((rowB>>6)*Hh_ + j0 + (rowB&63))*ldw + k0 + csw;
            gload16(g, BsBase + c*512);
        }
    }
}

template<int GN>
__device__ __forceinline__ void compute_tile64(
    f32x4 (&acc)[4][2][2],
    const ushort (&As)[BM][BK], const ushort (&Bs)[192][BK],
    int lane, int wm, int wn)
{
#pragma unroll
    for (int s = 0; s < 2; ++s) {
        const int colr = (((s*4 + (lane>>4)) ^ (lane & 7)) * 8);  // swizzled read col
        bf16x8 af[2];
#pragma unroll
        for (int fm = 0; fm < 2; ++fm)
            af[fm] = *(const bf16x8*)&As[wm*32 + fm*16 + (lane&15)][colr];
#pragma unroll
        for (int g = 0; g < 3; ++g) {
            const int gi = (g == 2) ? GN : g;
#pragma unroll
            for (int fn = 0; fn < 2; ++fn) {
                const bf16x8 bv = *(const bf16x8*)&Bs[g*64 + wn*32 + fn*16 + (lane&15)][colr];
#pragma unroll
                for (int fm = 0; fm < 2; ++fm)
                    acc[gi][fm][fn] = __builtin_amdgcn_mfma_f32_16x16x32_bf16(
                        af[fm], bv, acc[gi][fm][fn], 0, 0, 0);
            }
        }
    }
}

template<bool HAS_H>
__global__ __launch_bounds__(256, 4) void gru2_kernel(
    const ushort* __restrict__ X0, const ushort* __restrict__ X1,
    const ushort* __restrict__ Hb0, const ushort* __restrict__ Hb1,
    const float*  __restrict__ Hf0, const float*  __restrict__ Hf1,
    const ushort* __restrict__ Wih0, const ushort* __restrict__ Wih1,
    const ushort* __restrict__ Whh0, const ushort* __restrict__ Whh1,
    const float* __restrict__ bih0, const float* __restrict__ bih1,
    const float* __restrict__ bhh0, const float* __restrict__ bhh1,
    float* __restrict__ HoutF0, float* __restrict__ HoutF1,
    ushort* __restrict__ HoutB0, ushort* __restrict__ HoutB1,
    ushort* __restrict__ emb0, ushort* __restrict__ emb1)
{
    __shared__ __align__(16) ushort As[BM][BK];   // 8 KB
    __shared__ __align__(16) ushort Bs[192][BK];  // 24 KB

    const int sel = blockIdx.z;
    const ushort* Xb   = sel ? X1 : X0;
    const ushort* Hb   = sel ? Hb1 : Hb0;
    const float*  Hf   = sel ? Hf1 : Hf0;
    const ushort* Wihb = sel ? Wih1 : Wih0;
    const ushort* Whhb = sel ? Whh1 : Whh0;
    const float*  bih  = sel ? bih1 : bih0;
    const float*  bhh  = sel ? bhh1 : bhh0;
    float*  Hout_f = sel ? HoutF1 : HoutF0;
    ushort* Hout_b = sel ? HoutB1 : HoutB0;
    ushort* emb_b  = sel ? emb1 : emb0;

    const int tid = threadIdx.x;
    const int lane = tid & 63, wid = tid >> 6;
    const int wm = wid >> 1, wn = wid & 1;

    // XCD remap: flat = ((ib/8)*4 + jb)*8 + ib%8  (bijective on [0,1024))
    const int flat = blockIdx.x;
    const int i8   = flat & 7;
    const int rest = flat >> 3;
    const int jb   = rest & 3;
    const int ib   = (rest >> 2) * 8 + i8;
    const int i0 = ib * BM;
    const int j0 = jb * BNG;

    f32x4 acc[4][2][2] = {};   // [r,z,n_ih | n_hh][fm][fn]

    for (int k0 = 0; k0 < H_; k0 += BK) {
        stage_tiles64(Xb, H_, Wihb, H_, i0, j0, k0, &As[0][0], &Bs[0][0], lane, wid);
        __syncthreads();
        compute_tile64<2>(acc, As, Bs, lane, wm, wn);
        __syncthreads();
    }
    if (HAS_H) {
        for (int k0 = 0; k0 < Hh_; k0 += BK) {
            stage_tiles64(Hb, Hh_, Whhb, Hh_, i0, j0, k0, &As[0][0], &Bs[0][0], lane, wid);
            __syncthreads();
            compute_tile64<3>(acc, As, Bs, lane, wm, wn);
            __syncthreads();
        }
    }

#pragma unroll
    for (int fn = 0; fn < 2; ++fn) {
        const int j = j0 + wn*32 + fn*16 + (lane & 15);
        const float bri = bih[j],       brh = bhh[j];
        const float bzi = bih[Hh_ + j], bzh = bhh[Hh_ + j];
        const float bni = bih[2*Hh_+j], bnh = bhh[2*Hh_ + j];
#pragma unroll
        for (int fm = 0; fm < 2; ++fm) {
#pragma unroll
            for (int r = 0; r < 4; ++r) {
                const int i = i0 + wm*32 + fm*16 + (lane >> 4)*4 + r;
                const float xr = acc[0][fm][fn][r] + bri + brh;
                const float xz = acc[1][fm][fn][r] + bzi + bzh;
                const float xn = acc[2][fm][fn][r] + bni;
                float hn = bnh, hprev = 0.f;
                if (HAS_H) { hn += acc[3][fm][fn][r]; hprev = Hf[(size_t)i*Hh_ + j]; }
                const float rg = sigmoidf_(xr);
                const float zg = sigmoidf_(xz);
                const float ng = tanhf(xn + rg * hn);
                const float hp = (1.f - zg) * ng + zg * hprev;
                if (HAS_H) {
                    emb_b[(size_t)i*H_ + j] = f2bf(0.5f * (hprev + hp));
                } else {
                    Hout_f[(size_t)i*Hh_ + j] = hp;
                    Hout_b[(size_t)i*Hh_ + j] = f2bf(hp);
                }
            }
        }
    }
}

// ---------------------------------------------------------------------------
// block reductions
// ---------------------------------------------------------------------------
template<int NT>
__device__ __forceinline__ float block_reduce_max(float v, float* red) {
#pragma unroll
    for (int o = 32; o > 0; o >>= 1) v = fmaxf(v, __shfl_down(v, o));
    const int wid = threadIdx.x >> 6;
    if ((threadIdx.x & 63) == 0) red[wid] = v;
    __syncthreads();
    if (threadIdx.x == 0) {
        float m = red[0];
#pragma unroll
        for (int i = 1; i < NT/64; ++i) m = fmaxf(m, red[i]);
        red[0] = m;
    }
    __syncthreads();
    const float r = red[0];
    __syncthreads();
    return r;
}

template<int NT>
__device__ __forceinline__ float block_reduce_sum(float v, float* red) {
#pragma unroll
    for (int o = 32; o > 0; o >>= 1) v += __shfl_down(v, o);
    const int wid = threadIdx.x >> 6;
    if ((threadIdx.x & 63) == 0) red[wid] = v;
    __syncthreads();
    if (threadIdx.x == 0) {
        float m = red[0];
#pragma unroll
        for (int i = 1; i < NT/64; ++i) m += red[i];
        red[0] = m;
    }
    __syncthreads();
    const float r = red[0];
    __syncthreads();
    return r;
}

// ---------------------------------------------------------------------------
// attention, split for parallelism.
// A: logits.  grid (16, T), 256 threads: 64 u/block, 4 threads per u.
// ---------------------------------------------------------------------------
__global__ __launch_bounds__(256) void attn_logits_kernel(
    const ushort* __restrict__ db, const float* __restrict__ key,
    const int* __restrict__ attn_mask, float* __restrict__ alog)
{
    const int t = blockIdx.y;
    const int tid = threadIdx.x;
    const int u = blockIdx.x*64 + (tid >> 2);
    const int kq = (tid & 3) * 128;

    const bf16x8* r8 = (const bf16x8*)(db + ((size_t)t*U_ + u)*H_ + kq);
    const float* kp = key + t*H_ + kq;
    float s = 0.f;
#pragma unroll
    for (int k8 = 0; k8 < 16; ++k8) {
        const bf16x8 v = r8[k8];
#pragma unroll
        for (int j = 0; j < 8; ++j)
            s = fmaf(kp[k8*8 + j], bf2f((ushort)v[j]), s);
    }
    s += __shfl_xor(s, 1);
    s += __shfl_xor(s, 2);
    if ((tid & 3) == 0)
        alog[t*U_ + u] = attn_mask[t*U_ + u] ? s : -1e9f;
}

// B: softmax -> weights. grid T, 512 threads.
__global__ __launch_bounds__(512) void attn_softmax_kernel(
    const float* __restrict__ alog, float* __restrict__ aw)
{
    __shared__ float red[8];
    const int t = blockIdx.x, tid = threadIdx.x;
    const float v0 = alog[t*U_ + tid], v1 = alog[t*U_ + tid + 512];
    const float m = block_reduce_max<512>(fmaxf(v0, v1), red);
    const float e0 = expf(v0 - m), e1 = expf(v1 - m);
    const float s = block_reduce_sum<512>(e0 + e1, red);
    const float inv = 1.f / s;
    aw[t*U_ + tid] = e0 * inv;
    aw[t*U_ + tid + 512] = e1 * inv;
}

// C: weighted sum partials. grid (8, T), 512 threads: 128 u per block.
__global__ __launch_bounds__(512) void attn_wsum_kernel(
    const ushort* __restrict__ db, const float* __restrict__ aw,
    float* __restrict__ part)
{
    const int t = blockIdx.y, u0 = blockIdx.x * 128;
    const int h = threadIdx.x;
    float a = 0.f;
    for (int u = 0; u < 128; ++u)
        a = fmaf(aw[t*U_ + u0 + u], bf2f(db[((size_t)t*U_ + u0 + u)*H_ + h]), a);
    part[((size_t)blockIdx.x*T_ + t)*H_ + h] = a;
}

// ---------------------------------------------------------------------------
// feature = finf + sum(part) -> bf16
// ---------------------------------------------------------------------------
__global__ __launch_bounds__(256) void featcvt_kernel(
    const float* __restrict__ finf, const float* __restrict__ part,
    ushort* __restrict__ featb)
{
    const int row = blockIdx.x;       // t*64+l
    const int t = row >> 6;
    const int h = threadIdx.x * 2;
    const float2 v = *(const float2*)(finf + (size_t)row*H_ + h);
    float ax = 0.f, ay = 0.f;
#pragma unroll
    for (int p = 0; p < 8; ++p) {
        const float2 a = *(const float2*)(part + ((size_t)p*T_ + t)*H_ + h);
        ax += a.x; ay += a.y;
    }
    ushort2 o; o.x = f2bf(v.x + ax); o.y = f2bf(v.y + ay);
    *(ushort2*)(featb + (size_t)row*H_ + h) = o;
}

// ---------------------------------------------------------------------------
// ff = tanh(featb @ Wb^T + bb) -> bf16.  M=1024, N=512, K=512. Swizzled LDS.
// ---------------------------------------------------------------------------
__global__ __launch_bounds__(256) void ffgemm_kernel(
    const ushort* __restrict__ featb, const ushort* __restrict__ Wbb,
    const float* __restrict__ bb, ushort* __restrict__ ffb)
{
    __shared__ __align__(16) ushort As[128][BK];  // 16 KB
    __shared__ __align__(16) ushort Bs[64][BK];   // 8 KB

    const int tid = threadIdx.x;
    const int lane = tid & 63, wid = tid >> 6;
    const int wm = wid >> 1, wn = wid & 1;
    const int i0 = blockIdx.y * 128;
    const int j0 = blockIdx.x * 64;
    const int csw  = (((lane & 7) ^ (lane >> 3)) * 8);
    const int rsub = lane >> 3;

    f32x4 acc[4][2] = {};

    for (int k0 = 0; k0 < H_; k0 += BK) {
#pragma unroll
        for (int cc = wid; cc < 24; cc += 4) {
            if (cc < 16) {
                const ushort* g = featb + (size_t)(i0 + cc*8 + rsub)*H_ + k0 + csw;
                gload16(g, &As[0][0] + cc*512);
            } else {
                const int c = cc - 16;
                const ushort* g = Wbb + (size_t)(j0 + c*8 + rsub)*H_ + k0 + csw;
                gload16(g, &Bs[0][0] + c*512);
            }
        }
        __syncthreads();
#pragma unroll
        for (int s = 0; s < 2; ++s) {
            const int colr = (((s*4 + (lane>>4)) ^ (lane & 7)) * 8);
            bf16x8 af[4];
#pragma unroll
            for (int fm = 0; fm < 4; ++fm)
                af[fm] = *(const bf16x8*)&As[wm*64 + fm*16 + (lane&15)][colr];
#pragma unroll
            for (int fn = 0; fn < 2; ++fn) {
                const bf16x8 bv = *(const bf16x8*)&Bs[wn*32 + fn*16 + (lane&15)][colr];
#pragma unroll
                for (int fm = 0; fm < 4; ++fm)
                    acc[fm][fn] = __builtin_amdgcn_mfma_f32_16x16x32_bf16(
                        af[fm], bv, acc[fm][fn], 0, 0, 0);
            }
        }
        __syncthreads();
    }

#pragma unroll
    for (int fn = 0; fn < 2; ++fn) {
        const int j = j0 + wn*32 + fn*16 + (lane & 15);
        const float b = bb[j];
#pragma unroll
        for (int fm = 0; fm < 4; ++fm)
#pragma unroll
            for (int r = 0; r < 4; ++r) {
                const int i = i0 + wm*64 + fm*16 + (lane >> 4)*4 + r;
                ffb[(size_t)i*H_ + j] = f2bf(tanhf(acc[fm][fn][r] + b));
            }
    }
}

// ---------------------------------------------------------------------------
// logits[t*64+l, n] = ff[t*64+l,:] . V[n,:].  Swizzled LDS.
// ---------------------------------------------------------------------------
__global__ __launch_bounds__(256) void logits_kernel(
    const ushort* __restrict__ ffb, const ushort* __restrict__ dbb,
    const ushort* __restrict__ Kembb, float* __restrict__ logits)
{
    __shared__ __align__(16) ushort As[64][BK];   // 8 KB
    __shared__ __align__(16) ushort Bs[64][BK];   // 8 KB

    const int tid = threadIdx.x;
    const int lane = tid & 63, wid = tid >> 6;
    const int t = blockIdx.y;
    const int bx = blockIdx.x;
    const bool kw = (bx == 16);
    const int csw  = (((lane & 7) ^ (lane >> 3)) * 8);
    const int rsub = lane >> 3;

    f32x4 acc[4] = {};

    for (int k0 = 0; k0 < H_; k0 += BK) {
#pragma unroll
        for (int cc = wid; cc < 16; cc += 4) {
            if (cc < 8) {
                const ushort* g = ffb + (size_t)(t*64 + cc*8 + rsub)*H_ + k0 + csw;
                gload16(g, &As[0][0] + cc*512);
            } else {
                const int rloc = (cc-8)*8 + rsub;
                const ushort* g = kw ? (Kembb + (size_t)rloc*H_ + k0 + csw)
                                     : (dbb + (size_t)(t*U_ + bx*64 + rloc)*H_ + k0 + csw);
                gload16(g, &Bs[0][0] + (cc-8)*512);
            }
        }
        __syncthreads();
#pragma unroll
        for (int s = 0; s < 2; ++s) {
            const int colr = (((s*4 + (lane>>4)) ^ (lane & 7)) * 8);
            const bf16x8 af = *(const bf16x8*)&As[wid*16 + (lane&15)][colr];
#pragma unroll
            for (int fn = 0; fn < 4; ++fn) {
                const bf16x8 bv = *(const bf16x8*)&Bs[fn*16 + (lane&15)][colr];
                acc[fn] = __builtin_amdgcn_mfma_f32_16x16x32_bf16(af, bv, acc[fn], 0, 0, 0);
            }
        }
        __syncthreads();
    }

    const int ncols = U_ + K_;
#pragma unroll
    for (int fn = 0; fn < 4; ++fn) {
        const int jg = (kw ? U_ : bx*64) + fn*16 + (lane & 15);
#pragma unroll
        for (int r = 0; r < 4; ++r) {
            const int i = t*64 + wid*16 + (lane >> 4)*4 + r;
            logits[(size_t)i*ncols + jg] = acc[fn][r];
        }
    }
}

// ---------------------------------------------------------------------------
// per-row log_softmax over 1088 logits
// ---------------------------------------------------------------------------
__global__ __launch_bounds__(256) void lsm_kernel(
    const float* __restrict__ logits, float* __restrict__ out)
{
    __shared__ float sl[U_ + K_];
    __shared__ float red[4];
    const int row = blockIdx.x;
    const int tid = threadIdx.x;
    const int ncols = U_ + K_;

    float m = -3.4e38f;
    for (int idx = tid; idx < ncols; idx += 256) {
        const float v = logits[(size_t)row*ncols + idx];
        sl[idx] = v;
        m = fmaxf(m, v);
    }
    __syncthreads();
    m = block_reduce_max<256>(m, red);

    float s = 0.f;
    for (int idx = tid; idx < ncols; idx += 256) s += expf(sl[idx] - m);
    s = block_reduce_sum<256>(s, red);
    const float lse = m + logf(s);

    for (int idx = tid; idx < ncols; idx += 256)
        out[(size_t)row*ncols + idx] = sl[idx] - lse;
}

// ---------------------------------------------------------------------------
extern "C" void kernel_launch(void* const* d_in, const int* in_sizes, int n_in,
                              void* d_out, int out_size, void* d_ws, size_t ws_size,
                              hipStream_t stream)
{
    const float* feat  = (const float*)d_in[0];
    const float* key   = (const float*)d_in[1];
    const float* finf  = (const float*)d_in[2];
    const float* Wih_f = (const float*)d_in[3];
    const float* Whh_f = (const float*)d_in[4];
    const float* bih_f = (const float*)d_in[5];
    const float* bhh_f = (const float*)d_in[6];
    const float* Wih_b = (const float*)d_in[7];
    const float* Whh_b = (const float*)d_in[8];
    const float* bih_b = (const float*)d_in[9];
    const float* bhh_b = (const float*)d_in[10];
    const float* Wb    = (const float*)d_in[11];
    const float* bb    = (const float*)d_in[12];
    const float* Kemb  = (const float*)d_in[13];
    const int* col_idx  = (const int*)d_in[14];
    const int* col_mask = (const int*)d_in[15];
    const int* tab_idx  = (const int*)d_in[16];
    const int* tab_mask = (const int*)d_in[17];
    const int* attn_mask= (const int*)d_in[18];
    float* out = (float*)d_out;

    char* p = (char*)d_ws;
    ushort* wbf  = (ushort*)p;  p += (size_t)(2*(S0_+S1_) + WB_ + KE_)*2;  // 2.95 MB
    ushort* x1b  = (ushort*)p;  p += (size_t)M_*H_*2;                      // 16.8 MB
    ushort* x2b  = (ushort*)p;  p += (size_t)M_*H_*2;
    float*  f1f  = (float*)p;   p += (size_t)M_*Hh_*4;
    ushort* f1b  = (ushort*)p;  p += (size_t)M_*Hh_*2;
    float*  b1f  = (float*)p;   p += (size_t)M_*Hh_*4;
    ushort* b1b  = (ushort*)p;  p += (size_t)M_*Hh_*2;
    ushort* dbb  = (ushort*)p;  p += (size_t)M_*H_*2;                      // 16.8 MB
    float*  alog = (float*)p;   p += (size_t)T_*U_*4;
    float*  aw   = (float*)p;   p += (size_t)T_*U_*4;
    float*  part = (float*)p;   p += (size_t)8*T_*H_*4;
    ushort* featb= (ushort*)p;  p += (size_t)T_*L_*H_*2;
    ushort* ffb  = (ushort*)p;  p += (size_t)T_*L_*H_*2;
    float*  lg   = (float*)p;   p += (size_t)T_*L_*(U_+K_)*4;              // 4.45 MB

    const ushort* Wihf_b = wbf;
    const ushort* Whhf_b = wbf + S0_;
    const ushort* Wihb_b = wbf + S0_ + S1_;
    const ushort* Whhb_b = wbf + 2*S0_ + S1_;
    const ushort* Wbb    = wbf + 2*(S0_ + S1_);
    const ushort* Kembb  = wbf + 2*(S0_ + S1_) + WB_;

    wcvt_kernel<<<(2*(S0_+S1_) + WB_ + KE_)/1024, 256, 0, stream>>>(
        Wih_f, Whh_f, Wih_b, Whh_b, Wb, Kemb, wbf);

    meanpool_kernel<<<dim3(U_, T_), 256, 0, stream>>>(
        feat, col_idx, col_mask, tab_idx, tab_mask, x1b, x2b);

    dim3 gg((M_/BM)*(Hh_/BNG), 1, 2);   // (1024, 1, 2), XCD-remapped in-kernel
    gru2_kernel<false><<<gg, 256, 0, stream>>>(
        x1b, x2b, nullptr, nullptr, nullptr, nullptr,
        Wihf_b, Wihb_b, Whhf_b, Whhb_b, bih_f, bih_b, bhh_f, bhh_b,
        f1f, b1f, f1b, b1b, nullptr, nullptr);
    gru2_kernel<true><<<gg, 256, 0, stream>>>(
        x2b, x1b, f1b, b1b, f1f, b1f,
        Wihf_b, Wihb_b, Whhf_b, Whhb_b, bih_f, bih_b, bhh_f, bhh_b,
        nullptr, nullptr, nullptr, nullptr, dbb, dbb + Hh_);

    attn_logits_kernel<<<dim3(16, T_), 256, 0, stream>>>(dbb, key, attn_mask, alog);
    attn_softmax_kernel<<<T_, 512, 0, stream>>>(alog, aw);
    attn_wsum_kernel<<<dim3(8, T_), 512, 0, stream>>>(dbb, aw, part);
    featcvt_kernel<<<T_*L_, 256, 0, stream>>>(finf, part, featb);
    ffgemm_kernel<<<dim3(H_/64, (T_*L_)/128), 256, 0, stream>>>(featb, Wbb, bb, ffb);
    logits_kernel<<<dim3(17, T_), 256, 0, stream>>>(ffb, dbb, Kembb, lg);
    lsm_kernel<<<T_*L_, 256, 0, stream>>>(lg, out);
}

// Round 9
// 264.466 us; speedup vs baseline: 5.7612x; 1.0976x over previous
//
#include <hip/hip_runtime.h>
#include <math.h>

#define T_  16
#define DB2_ 512
#define H_  512
#define Hh_ 256
#define U_  1024
#define MC_ 8
#define MT_ 4
#define L_  64
#define K_  64
#define M_  (T_*U_)   // 16384

#define BM 64
#define BNG 64
#define BK 64
#define S0_ (768*512)
#define S1_ (768*256)
#define WB_ (512*512)
#define KE_ (64*512)

typedef __attribute__((ext_vector_type(8))) short bf16x8;
typedef __attribute__((ext_vector_type(4))) float f32x4;

__device__ __forceinline__ float sigmoidf_(float x) { return 1.f / (1.f + expf(-x)); }

__device__ __forceinline__ ushort f2bf(float f) {
    union { float f; unsigned u; } v; v.f = f;
    const unsigned r = (v.u + 0x7FFFu + ((v.u >> 16) & 1u)) >> 16;
    return (ushort)r;
}
__device__ __forceinline__ float bf2f(ushort u) {
    union { unsigned u; float f; } v; v.u = ((unsigned)u) << 16; return v.f;
}

__device__ __forceinline__ void gload16(const void* g, void* l) {
    __builtin_amdgcn_global_load_lds(
        (const __attribute__((address_space(1))) void*)g,
        (__attribute__((address_space(3))) void*)l, 16, 0, 0);
}

// ---------------------------------------------------------------------------
// Kernel 0: convert weights to bf16: Wih_f|Whh_f|Wih_b|Whh_b|Wb|Kemb
// ---------------------------------------------------------------------------
__global__ __launch_bounds__(256) void wcvt_kernel(
    const float* __restrict__ w0, const float* __restrict__ w1,
    const float* __restrict__ w2, const float* __restrict__ w3,
    const float* __restrict__ w4, const float* __restrict__ w5,
    ushort* __restrict__ dst)
{
    const int idx = (blockIdx.x * 256 + threadIdx.x) * 4;
    const float* src; int local;
    if      (idx < S0_)                  { src = w0; local = idx; }
    else if (idx < S0_ + S1_)            { src = w1; local = idx - S0_; }
    else if (idx < 2*S0_ + S1_)          { src = w2; local = idx - S0_ - S1_; }
    else if (idx < 2*S0_ + 2*S1_)        { src = w3; local = idx - 2*S0_ - S1_; }
    else if (idx < 2*S0_ + 2*S1_ + WB_)  { src = w4; local = idx - 2*S0_ - 2*S1_; }
    else                                 { src = w5; local = idx - 2*S0_ - 2*S1_ - WB_; }
    const float4 v = *(const float4*)(src + local);
    ushort4 o; o.x = f2bf(v.x); o.y = f2bf(v.y); o.z = f2bf(v.z); o.w = f2bf(v.w);
    *(ushort4*)(dst + idx) = o;
}

// ---------------------------------------------------------------------------
// Kernel 1: masked mean pooling -> x1 (tab), x2 (col) in bf16
// ---------------------------------------------------------------------------
__global__ __launch_bounds__(256) void meanpool_kernel(
    const float* __restrict__ feat,
    const int* __restrict__ col_idx, const int* __restrict__ col_mask,
    const int* __restrict__ tab_idx, const int* __restrict__ tab_mask,
    ushort* __restrict__ x1, ushort* __restrict__ x2)
{
    const int u = blockIdx.x;
    const int t = blockIdx.y;
    const int tid = threadIdx.x;

    int ci[MC_], cm[MC_], ti[MT_], tm[MT_];
    float cc = 0.f, tc = 0.f;
#pragma unroll
    for (int m = 0; m < MC_; ++m) { ci[m] = col_idx[u*MC_+m]; cm[m] = col_mask[u*MC_+m]; cc += (float)cm[m]; }
#pragma unroll
    for (int m = 0; m < MT_; ++m) { ti[m] = tab_idx[u*MT_+m]; tm[m] = tab_mask[u*MT_+m]; tc += (float)tm[m]; }
    const float rc = 1.f / fmaxf(cc, 1.f);
    const float rt = 1.f / fmaxf(tc, 1.f);

    const float* fb = feat + (size_t)t * DB2_ * H_;
    const int h = tid * 2;

    float acx = 0.f, acy = 0.f, atx = 0.f, aty = 0.f;
#pragma unroll
    for (int m = 0; m < MC_; ++m) if (cm[m]) {
        const float2 v = *(const float2*)(fb + (size_t)ci[m]*H_ + h);
        acx += v.x; acy += v.y;
    }
#pragma unroll
    for (int m = 0; m < MT_; ++m) if (tm[m]) {
        const float2 v = *(const float2*)(fb + (size_t)ti[m]*H_ + h);
        atx += v.x; aty += v.y;
    }
    const size_t o = ((size_t)(t*U_ + u))*H_ + h;
    ushort2 c2; c2.x = f2bf(acx*rc); c2.y = f2bf(acy*rc);
    ushort2 t2; t2.x = f2bf(atx*rt); t2.y = f2bf(aty*rt);
    *(ushort2*)(x2 + o) = c2;
    *(ushort2*)(x1 + o) = t2;
}

// ---------------------------------------------------------------------------
// GRU cells via MFMA, swizzled LDS.  BM=64, 4 waves of 32x32x3gates.
// Staging addresses are hoisted out of the K-loop: 8 loop-carried pointers
// per wave (2 A + 6 B), incremented by BK, with fixed wave-uniform LDS dests.
// blockIdx.x is XCD-remapped so the 4 j-blocks of an X panel share an XCD L2.
// ---------------------------------------------------------------------------
template<int GN>
__device__ __forceinline__ void compute_tile64(
    f32x4 (&acc)[4][2][2],
    const ushort (&As)[BM][BK], const ushort (&Bs)[192][BK],
    int lane, int wm, int wn)
{
#pragma unroll
    for (int s = 0; s < 2; ++s) {
        const int colr = (((s*4 + (lane>>4)) ^ (lane & 7)) * 8);  // swizzled read col
        bf16x8 af[2];
#pragma unroll
        for (int fm = 0; fm < 2; ++fm)
            af[fm] = *(const bf16x8*)&As[wm*32 + fm*16 + (lane&15)][colr];
#pragma unroll
        for (int g = 0; g < 3; ++g) {
            const int gi = (g == 2) ? GN : g;
#pragma unroll
            for (int fn = 0; fn < 2; ++fn) {
                const bf16x8 bv = *(const bf16x8*)&Bs[g*64 + wn*32 + fn*16 + (lane&15)][colr];
#pragma unroll
                for (int fm = 0; fm < 2; ++fm)
                    acc[gi][fm][fn] = __builtin_amdgcn_mfma_f32_16x16x32_bf16(
                        af[fm], bv, acc[gi][fm][fn], 0, 0, 0);
            }
        }
    }
}

template<bool HAS_H>
__global__ __launch_bounds__(256, 4) void gru2_kernel(
    const ushort* __restrict__ X0, const ushort* __restrict__ X1,
    const ushort* __restrict__ Hb0, const ushort* __restrict__ Hb1,
    const float*  __restrict__ Hf0, const float*  __restrict__ Hf1,
    const ushort* __restrict__ Wih0, const ushort* __restrict__ Wih1,
    const ushort* __restrict__ Whh0, const ushort* __restrict__ Whh1,
    const float* __restrict__ bih0, const float* __restrict__ bih1,
    const float* __restrict__ bhh0, const float* __restrict__ bhh1,
    float* __restrict__ HoutF0, float* __restrict__ HoutF1,
    ushort* __restrict__ HoutB0, ushort* __restrict__ HoutB1,
    ushort* __restrict__ emb0, ushort* __restrict__ emb1)
{
    __shared__ __align__(16) ushort As[BM][BK];   // 8 KB
    __shared__ __align__(16) ushort Bs[192][BK];  // 24 KB

    const int sel = blockIdx.z;
    const ushort* Xb   = sel ? X1 : X0;
    const ushort* Hb   = sel ? Hb1 : Hb0;
    const float*  Hf   = sel ? Hf1 : Hf0;
    const ushort* Wihb = sel ? Wih1 : Wih0;
    const ushort* Whhb = sel ? Whh1 : Whh0;
    const float*  bih  = sel ? bih1 : bih0;
    const float*  bhh  = sel ? bhh1 : bhh0;
    float*  Hout_f = sel ? HoutF1 : HoutF0;
    ushort* Hout_b = sel ? HoutB1 : HoutB0;
    ushort* emb_b  = sel ? emb1 : emb0;

    const int tid = threadIdx.x;
    const int lane = tid & 63, wid = tid >> 6;
    const int wm = wid >> 1, wn = wid & 1;

    // XCD remap: flat = ((ib/8)*4 + jb)*8 + ib%8  (bijective on [0,1024))
    const int flat = blockIdx.x;
    const int i8   = flat & 7;
    const int rest = flat >> 3;
    const int jb   = rest & 3;
    const int ib   = (rest >> 2) * 8 + i8;
    const int i0 = ib * BM;
    const int j0 = jb * BNG;

    const int csw  = (((lane & 7) ^ (lane >> 3)) * 8);
    const int rsub = lane >> 3;

    // fixed wave-uniform LDS destinations
    ushort* const ldsA0 = &As[0][0] + (size_t)wid*512;
    ushort* const ldsA1 = &As[0][0] + (size_t)(wid+4)*512;
    ushort* ldsB[6];
#pragma unroll
    for (int s = 0; s < 6; ++s) ldsB[s] = &Bs[0][0] + (size_t)(wid + 4*s)*512;

    f32x4 acc[4][2][2] = {};   // [r,z,n_ih | n_hh][fm][fn]

    // ---- phase 1: X @ Wih^T ----
    {
        const ushort* ga0 = Xb + (size_t)(i0 + wid*8     + rsub)*H_ + csw;
        const ushort* ga1 = Xb + (size_t)(i0 + (wid+4)*8 + rsub)*H_ + csw;
        const ushort* gb[6];
#pragma unroll
        for (int s = 0; s < 6; ++s) {
            const int rowB = (wid + 4*s)*8 + rsub;
            gb[s] = Wihb + (size_t)((rowB>>6)*Hh_ + j0 + (rowB&63))*H_ + csw;
        }
        for (int k0 = 0; k0 < H_; k0 += BK) {
            gload16(ga0, ldsA0);
            gload16(ga1, ldsA1);
#pragma unroll
            for (int s = 0; s < 6; ++s) gload16(gb[s], ldsB[s]);
            ga0 += BK; ga1 += BK;
#pragma unroll
            for (int s = 0; s < 6; ++s) gb[s] += BK;
            __syncthreads();
            compute_tile64<2>(acc, As, Bs, lane, wm, wn);
            __syncthreads();
        }
    }
    // ---- phase 2: H @ Whh^T ----
    if (HAS_H) {
        const ushort* ga0 = Hb + (size_t)(i0 + wid*8     + rsub)*Hh_ + csw;
        const ushort* ga1 = Hb + (size_t)(i0 + (wid+4)*8 + rsub)*Hh_ + csw;
        const ushort* gb[6];
#pragma unroll
        for (int s = 0; s < 6; ++s) {
            const int rowB = (wid + 4*s)*8 + rsub;
            gb[s] = Whhb + (size_t)((rowB>>6)*Hh_ + j0 + (rowB&63))*Hh_ + csw;
        }
        for (int k0 = 0; k0 < Hh_; k0 += BK) {
            gload16(ga0, ldsA0);
            gload16(ga1, ldsA1);
#pragma unroll
            for (int s = 0; s < 6; ++s) gload16(gb[s], ldsB[s]);
            ga0 += BK; ga1 += BK;
#pragma unroll
            for (int s = 0; s < 6; ++s) gb[s] += BK;
            __syncthreads();
            compute_tile64<3>(acc, As, Bs, lane, wm, wn);
            __syncthreads();
        }
    }

#pragma unroll
    for (int fn = 0; fn < 2; ++fn) {
        const int j = j0 + wn*32 + fn*16 + (lane & 15);
        const float bri = bih[j],       brh = bhh[j];
        const float bzi = bih[Hh_ + j], bzh = bhh[Hh_ + j];
        const float bni = bih[2*Hh_+j], bnh = bhh[2*Hh_ + j];
#pragma unroll
        for (int fm = 0; fm < 2; ++fm) {
#pragma unroll
            for (int r = 0; r < 4; ++r) {
                const int i = i0 + wm*32 + fm*16 + (lane >> 4)*4 + r;
                const float xr = acc[0][fm][fn][r] + bri + brh;
                const float xz = acc[1][fm][fn][r] + bzi + bzh;
                const float xn = acc[2][fm][fn][r] + bni;
                float hn = bnh, hprev = 0.f;
                if (HAS_H) { hn += acc[3][fm][fn][r]; hprev = Hf[(size_t)i*Hh_ + j]; }
                const float rg = sigmoidf_(xr);
                const float zg = sigmoidf_(xz);
                const float ng = tanhf(xn + rg * hn);
                const float hp = (1.f - zg) * ng + zg * hprev;
                if (HAS_H) {
                    emb_b[(size_t)i*H_ + j] = f2bf(0.5f * (hprev + hp));
                } else {
                    Hout_f[(size_t)i*Hh_ + j] = hp;
                    Hout_b[(size_t)i*Hh_ + j] = f2bf(hp);
                }
            }
        }
    }
}

// ---------------------------------------------------------------------------
// block reductions
// ---------------------------------------------------------------------------
template<int NT>
__device__ __forceinline__ float block_reduce_max(float v, float* red) {
#pragma unroll
    for (int o = 32; o > 0; o >>= 1) v = fmaxf(v, __shfl_down(v, o));
    const int wid = threadIdx.x >> 6;
    if ((threadIdx.x & 63) == 0) red[wid] = v;
    __syncthreads();
    if (threadIdx.x == 0) {
        float m = red[0];
#pragma unroll
        for (int i = 1; i < NT/64; ++i) m = fmaxf(m, red[i]);
        red[0] = m;
    }
    __syncthreads();
    const float r = red[0];
    __syncthreads();
    return r;
}

template<int NT>
__device__ __forceinline__ float block_reduce_sum(float v, float* red) {
#pragma unroll
    for (int o = 32; o > 0; o >>= 1) v += __shfl_down(v, o);
    const int wid = threadIdx.x >> 6;
    if ((threadIdx.x & 63) == 0) red[wid] = v;
    __syncthreads();
    if (threadIdx.x == 0) {
        float m = red[0];
#pragma unroll
        for (int i = 1; i < NT/64; ++i) m += red[i];
        red[0] = m;
    }
    __syncthreads();
    const float r = red[0];
    __syncthreads();
    return r;
}

// ---------------------------------------------------------------------------
// attention, split for parallelism.
// A: logits.  grid (16, T), 256 threads: 64 u/block, 4 threads per u.
// ---------------------------------------------------------------------------
__global__ __launch_bounds__(256) void attn_logits_kernel(
    const ushort* __restrict__ db, const float* __restrict__ key,
    const int* __restrict__ attn_mask, float* __restrict__ alog)
{
    const int t = blockIdx.y;
    const int tid = threadIdx.x;
    const int u = blockIdx.x*64 + (tid >> 2);
    const int kq = (tid & 3) * 128;

    const bf16x8* r8 = (const bf16x8*)(db + ((size_t)t*U_ + u)*H_ + kq);
    const float* kp = key + t*H_ + kq;
    float s = 0.f;
#pragma unroll
    for (int k8 = 0; k8 < 16; ++k8) {
        const bf16x8 v = r8[k8];
#pragma unroll
        for (int j = 0; j < 8; ++j)
            s = fmaf(kp[k8*8 + j], bf2f((ushort)v[j]), s);
    }
    s += __shfl_xor(s, 1);
    s += __shfl_xor(s, 2);
    if ((tid & 3) == 0)
        alog[t*U_ + u] = attn_mask[t*U_ + u] ? s : -1e9f;
}

// B: softmax -> weights. grid T, 512 threads.
__global__ __launch_bounds__(512) void attn_softmax_kernel(
    const float* __restrict__ alog, float* __restrict__ aw)
{
    __shared__ float red[8];
    const int t = blockIdx.x, tid = threadIdx.x;
    const float v0 = alog[t*U_ + tid], v1 = alog[t*U_ + tid + 512];
    const float m = block_reduce_max<512>(fmaxf(v0, v1), red);
    const float e0 = expf(v0 - m), e1 = expf(v1 - m);
    const float s = block_reduce_sum<512>(e0 + e1, red);
    const float inv = 1.f / s;
    aw[t*U_ + tid] = e0 * inv;
    aw[t*U_ + tid + 512] = e1 * inv;
}

// C: weighted sum partials. grid (8, T), 512 threads = 8 u-slices x 64 h-octets.
// bf16x8 vector loads; LDS reduce across the 8 u-slices.
__global__ __launch_bounds__(512) void attn_wsum_kernel(
    const ushort* __restrict__ db, const float* __restrict__ aw,
    float* __restrict__ part)
{
    __shared__ float sred[8][64][8];   // 16 KB
    const int t = blockIdx.y, u0 = blockIdx.x * 128;
    const int usub = threadIdx.x >> 6;   // 0..7
    const int h8   = threadIdx.x & 63;   // 0..63

    float a[8] = {};
    for (int uu = 0; uu < 16; ++uu) {
        const int u = u0 + usub*16 + uu;
        const float w = aw[t*U_ + u];
        const bf16x8 v = *(const bf16x8*)(db + ((size_t)t*U_ + u)*H_ + h8*8);
#pragma unroll
        for (int j = 0; j < 8; ++j) a[j] = fmaf(w, bf2f((ushort)v[j]), a[j]);
    }
#pragma unroll
    for (int j = 0; j < 8; ++j) sred[usub][h8][j] = a[j];
    __syncthreads();

    const int h8r = threadIdx.x >> 3;    // 0..63
    const int cr  = threadIdx.x & 7;     // 0..7
    float s = 0.f;
#pragma unroll
    for (int us = 0; us < 8; ++us) s += sred[us][h8r][cr];
    part[((size_t)blockIdx.x*T_ + t)*H_ + h8r*8 + cr] = s;
}

// ---------------------------------------------------------------------------
// feature = finf + sum(part) -> bf16
// ---------------------------------------------------------------------------
__global__ __launch_bounds__(256) void featcvt_kernel(
    const float* __restrict__ finf, const float* __restrict__ part,
    ushort* __restrict__ featb)
{
    const int row = blockIdx.x;       // t*64+l
    const int t = row >> 6;
    const int h = threadIdx.x * 2;
    const float2 v = *(const float2*)(finf + (size_t)row*H_ + h);
    float ax = 0.f, ay = 0.f;
#pragma unroll
    for (int p = 0; p < 8; ++p) {
        const float2 a = *(const float2*)(part + ((size_t)p*T_ + t)*H_ + h);
        ax += a.x; ay += a.y;
    }
    ushort2 o; o.x = f2bf(v.x + ax); o.y = f2bf(v.y + ay);
    *(ushort2*)(featb + (size_t)row*H_ + h) = o;
}

// ---------------------------------------------------------------------------
// ff = tanh(featb @ Wb^T + bb) -> bf16.  M=1024, N=512, K=512. Swizzled LDS.
// ---------------------------------------------------------------------------
__global__ __launch_bounds__(256) void ffgemm_kernel(
    const ushort* __restrict__ featb, const ushort* __restrict__ Wbb,
    const float* __restrict__ bb, ushort* __restrict__ ffb)
{
    __shared__ __align__(16) ushort As[128][BK];  // 16 KB
    __shared__ __align__(16) ushort Bs[64][BK];   // 8 KB

    const int tid = threadIdx.x;
    const int lane = tid & 63, wid = tid >> 6;
    const int wm = wid >> 1, wn = wid & 1;
    const int i0 = blockIdx.y * 128;
    const int j0 = blockIdx.x * 64;
    const int csw  = (((lane & 7) ^ (lane >> 3)) * 8);
    const int rsub = lane >> 3;

    f32x4 acc[4][2] = {};

    for (int k0 = 0; k0 < H_; k0 += BK) {
#pragma unroll
        for (int cc = wid; cc < 24; cc += 4) {
            if (cc < 16) {
                const ushort* g = featb + (size_t)(i0 + cc*8 + rsub)*H_ + k0 + csw;
                gload16(g, &As[0][0] + cc*512);
            } else {
                const int c = cc - 16;
                const ushort* g = Wbb + (size_t)(j0 + c*8 + rsub)*H_ + k0 + csw;
                gload16(g, &Bs[0][0] + c*512);
            }
        }
        __syncthreads();
#pragma unroll
        for (int s = 0; s < 2; ++s) {
            const int colr = (((s*4 + (lane>>4)) ^ (lane & 7)) * 8);
            bf16x8 af[4];
#pragma unroll
            for (int fm = 0; fm < 4; ++fm)
                af[fm] = *(const bf16x8*)&As[wm*64 + fm*16 + (lane&15)][colr];
#pragma unroll
            for (int fn = 0; fn < 2; ++fn) {
                const bf16x8 bv = *(const bf16x8*)&Bs[wn*32 + fn*16 + (lane&15)][colr];
#pragma unroll
                for (int fm = 0; fm < 4; ++fm)
                    acc[fm][fn] = __builtin_amdgcn_mfma_f32_16x16x32_bf16(
                        af[fm], bv, acc[fm][fn], 0, 0, 0);
            }
        }
        __syncthreads();
    }

#pragma unroll
    for (int fn = 0; fn < 2; ++fn) {
        const int j = j0 + wn*32 + fn*16 + (lane & 15);
        const float b = bb[j];
#pragma unroll
        for (int fm = 0; fm < 4; ++fm)
#pragma unroll
            for (int r = 0; r < 4; ++r) {
                const int i = i0 + wm*64 + fm*16 + (lane >> 4)*4 + r;
                ffb[(size_t)i*H_ + j] = f2bf(tanhf(acc[fm][fn][r] + b));
            }
    }
}

// ---------------------------------------------------------------------------
// logits[t*64+l, n] = ff[t*64+l,:] . V[n,:].  Swizzled LDS.
// ---------------------------------------------------------------------------
__global__ __launch_bounds__(256) void logits_kernel(
    const ushort* __restrict__ ffb, const ushort* __restrict__ dbb,
    const ushort* __restrict__ Kembb, float* __restrict__ logits)
{
    __shared__ __align__(16) ushort As[64][BK];   // 8 KB
    __shared__ __align__(16) ushort Bs[64][BK];   // 8 KB

    const int tid = threadIdx.x;
    const int lane = tid & 63, wid = tid >> 6;
    const int t = blockIdx.y;
    const int bx = blockIdx.x;
    const bool kw = (bx == 16);
    const int csw  = (((lane & 7) ^ (lane >> 3)) * 8);
    const int rsub = lane >> 3;

    f32x4 acc[4] = {};

    for (int k0 = 0; k0 < H_; k0 += BK) {
#pragma unroll
        for (int cc = wid; cc < 16; cc += 4) {
            if (cc < 8) {
                const ushort* g = ffb + (size_t)(t*64 + cc*8 + rsub)*H_ + k0 + csw;
                gload16(g, &As[0][0] + cc*512);
            } else {
                const int rloc = (cc-8)*8 + rsub;
                const ushort* g = kw ? (Kembb + (size_t)rloc*H_ + k0 + csw)
                                     : (dbb + (size_t)(t*U_ + bx*64 + rloc)*H_ + k0 + csw);
                gload16(g, &Bs[0][0] + (cc-8)*512);
            }
        }
        __syncthreads();
#pragma unroll
        for (int s = 0; s < 2; ++s) {
            const int colr = (((s*4 + (lane>>4)) ^ (lane & 7)) * 8);
            const bf16x8 af = *(const bf16x8*)&As[wid*16 + (lane&15)][colr];
#pragma unroll
            for (int fn = 0; fn < 4; ++fn) {
                const bf16x8 bv = *(const bf16x8*)&Bs[fn*16 + (lane&15)][colr];
                acc[fn] = __builtin_amdgcn_mfma_f32_16x16x32_bf16(af, bv, acc[fn], 0, 0, 0);
            }
        }
        __syncthreads();
    }

    const int ncols = U_ + K_;
#pragma unroll
    for (int fn = 0; fn < 4; ++fn) {
        const int jg = (kw ? U_ : bx*64) + fn*16 + (lane & 15);
#pragma unroll
        for (int r = 0; r < 4; ++r) {
            const int i = t*64 + wid*16 + (lane >> 4)*4 + r;
            logits[(size_t)i*ncols + jg] = acc[fn][r];
        }
    }
}

// ---------------------------------------------------------------------------
// per-row log_softmax over 1088 logits
// ---------------------------------------------------------------------------
__global__ __launch_bounds__(256) void lsm_kernel(
    const float* __restrict__ logits, float* __restrict__ out)
{
    __shared__ float sl[U_ + K_];
    __shared__ float red[4];
    const int row = blockIdx.x;
    const int tid = threadIdx.x;
    const int ncols = U_ + K_;

    float m = -3.4e38f;
    for (int idx = tid; idx < ncols; idx += 256) {
        const float v = logits[(size_t)row*ncols + idx];
        sl[idx] = v;
        m = fmaxf(m, v);
    }
    __syncthreads();
    m = block_reduce_max<256>(m, red);

    float s = 0.f;
    for (int idx = tid; idx < ncols; idx += 256) s += expf(sl[idx] - m);
    s = block_reduce_sum<256>(s, red);
    const float lse = m + logf(s);

    for (int idx = tid; idx < ncols; idx += 256)
        out[(size_t)row*ncols + idx] = sl[idx] - lse;
}

// ---------------------------------------------------------------------------
extern "C" void kernel_launch(void* const* d_in, const int* in_sizes, int n_in,
                              void* d_out, int out_size, void* d_ws, size_t ws_size,
                              hipStream_t stream)
{
    const float* feat  = (const float*)d_in[0];
    const float* key   = (const float*)d_in[1];
    const float* finf  = (const float*)d_in[2];
    const float* Wih_f = (const float*)d_in[3];
    const float* Whh_f = (const float*)d_in[4];
    const float* bih_f = (const float*)d_in[5];
    const float* bhh_f = (const float*)d_in[6];
    const float* Wih_b = (const float*)d_in[7];
    const float* Whh_b = (const float*)d_in[8];
    const float* bih_b = (const float*)d_in[9];
    const float* bhh_b = (const float*)d_in[10];
    const float* Wb    = (const float*)d_in[11];
    const float* bb    = (const float*)d_in[12];
    const float* Kemb  = (const float*)d_in[13];
    const int* col_idx  = (const int*)d_in[14];
    const int* col_mask = (const int*)d_in[15];
    const int* tab_idx  = (const int*)d_in[16];
    const int* tab_mask = (const int*)d_in[17];
    const int* attn_mask= (const int*)d_in[18];
    float* out = (float*)d_out;

    char* p = (char*)d_ws;
    ushort* wbf  = (ushort*)p;  p += (size_t)(2*(S0_+S1_) + WB_ + KE_)*2;  // 2.95 MB
    ushort* x1b  = (ushort*)p;  p += (size_t)M_*H_*2;                      // 16.8 MB
    ushort* x2b  = (ushort*)p;  p += (size_t)M_*H_*2;
    float*  f1f  = (float*)p;   p += (size_t)M_*Hh_*4;
    ushort* f1b  = (ushort*)p;  p += (size_t)M_*Hh_*2;
    float*  b1f  = (float*)p;   p += (size_t)M_*Hh_*4;
    ushort* b1b  = (ushort*)p;  p += (size_t)M_*Hh_*2;
    ushort* dbb  = (ushort*)p;  p += (size_t)M_*H_*2;                      // 16.8 MB
    float*  alog = (float*)p;   p += (size_t)T_*U_*4;
    float*  aw   = (float*)p;   p += (size_t)T_*U_*4;
    float*  part = (float*)p;   p += (size_t)8*T_*H_*4;
    ushort* featb= (ushort*)p;  p += (size_t)T_*L_*H_*2;
    ushort* ffb  = (ushort*)p;  p += (size_t)T_*L_*H_*2;
    float*  lg   = (float*)p;   p += (size_t)T_*L_*(U_+K_)*4;              // 4.45 MB

    const ushort* Wihf_b = wbf;
    const ushort* Whhf_b = wbf + S0_;
    const ushort* Wihb_b = wbf + S0_ + S1_;
    const ushort* Whhb_b = wbf + 2*S0_ + S1_;
    const ushort* Wbb    = wbf + 2*(S0_ + S1_);
    const ushort* Kembb  = wbf + 2*(S0_ + S1_) + WB_;

    wcvt_kernel<<<(2*(S0_+S1_) + WB_ + KE_)/1024, 256, 0, stream>>>(
        Wih_f, Whh_f, Wih_b, Whh_b, Wb, Kemb, wbf);

    meanpool_kernel<<<dim3(U_, T_), 256, 0, stream>>>(
        feat, col_idx, col_mask, tab_idx, tab_mask, x1b, x2b);

    dim3 gg((M_/BM)*(Hh_/BNG), 1, 2);   // (1024, 1, 2), XCD-remapped in-kernel
    gru2_kernel<false><<<gg, 256, 0, stream>>>(
        x1b, x2b, nullptr, nullptr, nullptr, nullptr,
        Wihf_b, Wihb_b, Whhf_b, Whhb_b, bih_f, bih_b, bhh_f, bhh_b,
        f1f, b1f, f1b, b1b, nullptr, nullptr);
    gru2_kernel<true><<<gg, 256, 0, stream>>>(
        x2b, x1b, f1b, b1b, f1f, b1f,
        Wihf_b, Wihb_b, Whhf_b, Whhb_b, bih_f, bih_b, bhh_f, bhh_b,
        nullptr, nullptr, nullptr, nullptr, dbb, dbb + Hh_);

    attn_logits_kernel<<<dim3(16, T_), 256, 0, stream>>>(dbb, key, attn_mask, alog);
    attn_softmax_kernel<<<T_, 512, 0, stream>>>(alog, aw);
    attn_wsum_kernel<<<dim3(8, T_), 512, 0, stream>>>(dbb, aw, part);
    featcvt_kernel<<<T_*L_, 256, 0, stream>>>(finf, part, featb);
    ffgemm_kernel<<<dim3(H_/64, (T_*L_)/128), 256, 0, stream>>>(featb, Wbb, bb, ffb);
    logits_kernel<<<dim3(17, T_), 256, 0, stream>>>(ffb, dbb, Kembb, lg);
    lsm_kernel<<<T_*L_, 256, 0, stream>>>(lg, out);
}

// Round 10
// 256.263 us; speedup vs baseline: 5.9456x; 1.0320x over previous
//
#include <hip/hip_runtime.h>
#include <math.h>

#define T_  16
#define DB2_ 512
#define H_  512
#define Hh_ 256
#define U_  1024
#define MC_ 8
#define MT_ 4
#define L_  64
#define K_  64
#define M_  (T_*U_)   // 16384

#define BM 64
#define BNG 64
#define BK 64
#define S0_ (768*512)
#define S1_ (768*256)
#define WB_ (512*512)
#define KE_ (64*512)

typedef __attribute__((ext_vector_type(8))) short bf16x8;
typedef __attribute__((ext_vector_type(4))) float f32x4;

// native-HW transcendentals: v_exp_f32 / v_log_f32 (libm expf/tanhf are
// multi-instruction range-reduced sequences — measured as the VALU 50% in R9)
__device__ __forceinline__ float sigmoidf_(float x) {
    return 1.f / (1.f + __expf(-x));     // exp(-x)->inf for large -x => 0, correct
}
__device__ __forceinline__ float tanhf_(float x) {
    const float xc = fminf(fmaxf(x, -10.f), 10.f);   // tanh saturates by |x|>9
    const float t = __expf(2.f * xc);
    return (t - 1.f) / (t + 1.f);
}

__device__ __forceinline__ ushort f2bf(float f) {
    union { float f; unsigned u; } v; v.f = f;
    const unsigned r = (v.u + 0x7FFFu + ((v.u >> 16) & 1u)) >> 16;
    return (ushort)r;
}
__device__ __forceinline__ float bf2f(ushort u) {
    union { unsigned u; float f; } v; v.u = ((unsigned)u) << 16; return v.f;
}

__device__ __forceinline__ void gload16(const void* g, void* l) {
    __builtin_amdgcn_global_load_lds(
        (const __attribute__((address_space(1))) void*)g,
        (__attribute__((address_space(3))) void*)l, 16, 0, 0);
}

// ---------------------------------------------------------------------------
// Kernel 0: convert weights to bf16: Wih_f|Whh_f|Wih_b|Whh_b|Wb|Kemb
// ---------------------------------------------------------------------------
__global__ __launch_bounds__(256) void wcvt_kernel(
    const float* __restrict__ w0, const float* __restrict__ w1,
    const float* __restrict__ w2, const float* __restrict__ w3,
    const float* __restrict__ w4, const float* __restrict__ w5,
    ushort* __restrict__ dst)
{
    const int idx = (blockIdx.x * 256 + threadIdx.x) * 4;
    const float* src; int local;
    if      (idx < S0_)                  { src = w0; local = idx; }
    else if (idx < S0_ + S1_)            { src = w1; local = idx - S0_; }
    else if (idx < 2*S0_ + S1_)          { src = w2; local = idx - S0_ - S1_; }
    else if (idx < 2*S0_ + 2*S1_)        { src = w3; local = idx - 2*S0_ - S1_; }
    else if (idx < 2*S0_ + 2*S1_ + WB_)  { src = w4; local = idx - 2*S0_ - 2*S1_; }
    else                                 { src = w5; local = idx - 2*S0_ - 2*S1_ - WB_; }
    const float4 v = *(const float4*)(src + local);
    ushort4 o; o.x = f2bf(v.x); o.y = f2bf(v.y); o.z = f2bf(v.z); o.w = f2bf(v.w);
    *(ushort4*)(dst + idx) = o;
}

// ---------------------------------------------------------------------------
// Kernel 1: masked mean pooling -> x1 (tab), x2 (col) in bf16
// ---------------------------------------------------------------------------
__global__ __launch_bounds__(256) void meanpool_kernel(
    const float* __restrict__ feat,
    const int* __restrict__ col_idx, const int* __restrict__ col_mask,
    const int* __restrict__ tab_idx, const int* __restrict__ tab_mask,
    ushort* __restrict__ x1, ushort* __restrict__ x2)
{
    const int u = blockIdx.x;
    const int t = blockIdx.y;
    const int tid = threadIdx.x;

    int ci[MC_], cm[MC_], ti[MT_], tm[MT_];
    float cc = 0.f, tc = 0.f;
#pragma unroll
    for (int m = 0; m < MC_; ++m) { ci[m] = col_idx[u*MC_+m]; cm[m] = col_mask[u*MC_+m]; cc += (float)cm[m]; }
#pragma unroll
    for (int m = 0; m < MT_; ++m) { ti[m] = tab_idx[u*MT_+m]; tm[m] = tab_mask[u*MT_+m]; tc += (float)tm[m]; }
    const float rc = 1.f / fmaxf(cc, 1.f);
    const float rt = 1.f / fmaxf(tc, 1.f);

    const float* fb = feat + (size_t)t * DB2_ * H_;
    const int h = tid * 2;

    float acx = 0.f, acy = 0.f, atx = 0.f, aty = 0.f;
#pragma unroll
    for (int m = 0; m < MC_; ++m) if (cm[m]) {
        const float2 v = *(const float2*)(fb + (size_t)ci[m]*H_ + h);
        acx += v.x; acy += v.y;
    }
#pragma unroll
    for (int m = 0; m < MT_; ++m) if (tm[m]) {
        const float2 v = *(const float2*)(fb + (size_t)ti[m]*H_ + h);
        atx += v.x; aty += v.y;
    }
    const size_t o = ((size_t)(t*U_ + u))*H_ + h;
    ushort2 c2; c2.x = f2bf(acx*rc); c2.y = f2bf(acy*rc);
    ushort2 t2; t2.x = f2bf(atx*rt); t2.y = f2bf(aty*rt);
    *(ushort2*)(x2 + o) = c2;
    *(ushort2*)(x1 + o) = t2;
}

// ---------------------------------------------------------------------------
// GRU cells via MFMA, swizzled LDS.  BM=64, 4 waves of 32x32x3gates.
// h-state carried in bf16 ONLY (f32 copy dropped: saved 16.8MB write + read).
// Staging addresses hoisted; blockIdx.x XCD-remapped.
// ---------------------------------------------------------------------------
template<int GN>
__device__ __forceinline__ void compute_tile64(
    f32x4 (&acc)[4][2][2],
    const ushort (&As)[BM][BK], const ushort (&Bs)[192][BK],
    int lane, int wm, int wn)
{
#pragma unroll
    for (int s = 0; s < 2; ++s) {
        const int colr = (((s*4 + (lane>>4)) ^ (lane & 7)) * 8);  // swizzled read col
        bf16x8 af[2];
#pragma unroll
        for (int fm = 0; fm < 2; ++fm)
            af[fm] = *(const bf16x8*)&As[wm*32 + fm*16 + (lane&15)][colr];
#pragma unroll
        for (int g = 0; g < 3; ++g) {
            const int gi = (g == 2) ? GN : g;
#pragma unroll
            for (int fn = 0; fn < 2; ++fn) {
                const bf16x8 bv = *(const bf16x8*)&Bs[g*64 + wn*32 + fn*16 + (lane&15)][colr];
#pragma unroll
                for (int fm = 0; fm < 2; ++fm)
                    acc[gi][fm][fn] = __builtin_amdgcn_mfma_f32_16x16x32_bf16(
                        af[fm], bv, acc[gi][fm][fn], 0, 0, 0);
            }
        }
    }
}

template<bool HAS_H>
__global__ __launch_bounds__(256, 4) void gru2_kernel(
    const ushort* __restrict__ X0, const ushort* __restrict__ X1,
    const ushort* __restrict__ Hb0, const ushort* __restrict__ Hb1,
    const ushort* __restrict__ Wih0, const ushort* __restrict__ Wih1,
    const ushort* __restrict__ Whh0, const ushort* __restrict__ Whh1,
    const float* __restrict__ bih0, const float* __restrict__ bih1,
    const float* __restrict__ bhh0, const float* __restrict__ bhh1,
    ushort* __restrict__ HoutB0, ushort* __restrict__ HoutB1,
    ushort* __restrict__ emb0, ushort* __restrict__ emb1)
{
    __shared__ __align__(16) ushort As[BM][BK];   // 8 KB
    __shared__ __align__(16) ushort Bs[192][BK];  // 24 KB

    const int sel = blockIdx.z;
    const ushort* Xb   = sel ? X1 : X0;
    const ushort* Hb   = sel ? Hb1 : Hb0;
    const ushort* Wihb = sel ? Wih1 : Wih0;
    const ushort* Whhb = sel ? Whh1 : Whh0;
    const float*  bih  = sel ? bih1 : bih0;
    const float*  bhh  = sel ? bhh1 : bhh0;
    ushort* Hout_b = sel ? HoutB1 : HoutB0;
    ushort* emb_b  = sel ? emb1 : emb0;

    const int tid = threadIdx.x;
    const int lane = tid & 63, wid = tid >> 6;
    const int wm = wid >> 1, wn = wid & 1;

    // XCD remap: flat = ((ib/8)*4 + jb)*8 + ib%8  (bijective on [0,1024))
    const int flat = blockIdx.x;
    const int i8   = flat & 7;
    const int rest = flat >> 3;
    const int jb   = rest & 3;
    const int ib   = (rest >> 2) * 8 + i8;
    const int i0 = ib * BM;
    const int j0 = jb * BNG;

    const int csw  = (((lane & 7) ^ (lane >> 3)) * 8);
    const int rsub = lane >> 3;

    // fixed wave-uniform LDS destinations
    ushort* const ldsA0 = &As[0][0] + (size_t)wid*512;
    ushort* const ldsA1 = &As[0][0] + (size_t)(wid+4)*512;
    ushort* ldsB[6];
#pragma unroll
    for (int s = 0; s < 6; ++s) ldsB[s] = &Bs[0][0] + (size_t)(wid + 4*s)*512;

    f32x4 acc[4][2][2] = {};   // [r,z,n_ih | n_hh][fm][fn]

    // ---- phase 1: X @ Wih^T ----
    {
        const ushort* ga0 = Xb + (size_t)(i0 + wid*8     + rsub)*H_ + csw;
        const ushort* ga1 = Xb + (size_t)(i0 + (wid+4)*8 + rsub)*H_ + csw;
        const ushort* gb[6];
#pragma unroll
        for (int s = 0; s < 6; ++s) {
            const int rowB = (wid + 4*s)*8 + rsub;
            gb[s] = Wihb + (size_t)((rowB>>6)*Hh_ + j0 + (rowB&63))*H_ + csw;
        }
        for (int k0 = 0; k0 < H_; k0 += BK) {
            gload16(ga0, ldsA0);
            gload16(ga1, ldsA1);
#pragma unroll
            for (int s = 0; s < 6; ++s) gload16(gb[s], ldsB[s]);
            ga0 += BK; ga1 += BK;
#pragma unroll
            for (int s = 0; s < 6; ++s) gb[s] += BK;
            __syncthreads();
            compute_tile64<2>(acc, As, Bs, lane, wm, wn);
            __syncthreads();
        }
    }
    // ---- phase 2: H @ Whh^T ----
    if (HAS_H) {
        const ushort* ga0 = Hb + (size_t)(i0 + wid*8     + rsub)*Hh_ + csw;
        const ushort* ga1 = Hb + (size_t)(i0 + (wid+4)*8 + rsub)*Hh_ + csw;
        const ushort* gb[6];
#pragma unroll
        for (int s = 0; s < 6; ++s) {
            const int rowB = (wid + 4*s)*8 + rsub;
            gb[s] = Whhb + (size_t)((rowB>>6)*Hh_ + j0 + (rowB&63))*Hh_ + csw;
        }
        for (int k0 = 0; k0 < Hh_; k0 += BK) {
            gload16(ga0, ldsA0);
            gload16(ga1, ldsA1);
#pragma unroll
            for (int s = 0; s < 6; ++s) gload16(gb[s], ldsB[s]);
            ga0 += BK; ga1 += BK;
#pragma unroll
            for (int s = 0; s < 6; ++s) gb[s] += BK;
            __syncthreads();
            compute_tile64<3>(acc, As, Bs, lane, wm, wn);
            __syncthreads();
        }
    }

#pragma unroll
    for (int fn = 0; fn < 2; ++fn) {
        const int j = j0 + wn*32 + fn*16 + (lane & 15);
        const float bri = bih[j],       brh = bhh[j];
        const float bzi = bih[Hh_ + j], bzh = bhh[Hh_ + j];
        const float bni = bih[2*Hh_+j], bnh = bhh[2*Hh_ + j];
#pragma unroll
        for (int fm = 0; fm < 2; ++fm) {
#pragma unroll
            for (int r = 0; r < 4; ++r) {
                const int i = i0 + wm*32 + fm*16 + (lane >> 4)*4 + r;
                const float xr = acc[0][fm][fn][r] + bri + brh;
                const float xz = acc[1][fm][fn][r] + bzi + bzh;
                const float xn = acc[2][fm][fn][r] + bni;
                float hn = bnh, hprev = 0.f;
                if (HAS_H) { hn += acc[3][fm][fn][r]; hprev = bf2f(Hb[(size_t)i*Hh_ + j]); }
                const float rg = sigmoidf_(xr);
                const float zg = sigmoidf_(xz);
                const float ng = tanhf_(xn + rg * hn);
                const float hp = (1.f - zg) * ng + zg * hprev;
                if (HAS_H) {
                    emb_b[(size_t)i*H_ + j] = f2bf(0.5f * (hprev + hp));
                } else {
                    Hout_b[(size_t)i*Hh_ + j] = f2bf(hp);
                }
            }
        }
    }
}

// ---------------------------------------------------------------------------
// block reductions
// ---------------------------------------------------------------------------
template<int NT>
__device__ __forceinline__ float block_reduce_max(float v, float* red) {
#pragma unroll
    for (int o = 32; o > 0; o >>= 1) v = fmaxf(v, __shfl_down(v, o));
    const int wid = threadIdx.x >> 6;
    if ((threadIdx.x & 63) == 0) red[wid] = v;
    __syncthreads();
    if (threadIdx.x == 0) {
        float m = red[0];
#pragma unroll
        for (int i = 1; i < NT/64; ++i) m = fmaxf(m, red[i]);
        red[0] = m;
    }
    __syncthreads();
    const float r = red[0];
    __syncthreads();
    return r;
}

template<int NT>
__device__ __forceinline__ float block_reduce_sum(float v, float* red) {
#pragma unroll
    for (int o = 32; o > 0; o >>= 1) v += __shfl_down(v, o);
    const int wid = threadIdx.x >> 6;
    if ((threadIdx.x & 63) == 0) red[wid] = v;
    __syncthreads();
    if (threadIdx.x == 0) {
        float m = red[0];
#pragma unroll
        for (int i = 1; i < NT/64; ++i) m += red[i];
        red[0] = m;
    }
    __syncthreads();
    const float r = red[0];
    __syncthreads();
    return r;
}

// ---------------------------------------------------------------------------
// attention, split for parallelism.
// A: logits.  grid (16, T), 256 threads: 64 u/block, 4 threads per u.
// ---------------------------------------------------------------------------
__global__ __launch_bounds__(256) void attn_logits_kernel(
    const ushort* __restrict__ db, const float* __restrict__ key,
    const int* __restrict__ attn_mask, float* __restrict__ alog)
{
    const int t = blockIdx.y;
    const int tid = threadIdx.x;
    const int u = blockIdx.x*64 + (tid >> 2);
    const int kq = (tid & 3) * 128;

    const bf16x8* r8 = (const bf16x8*)(db + ((size_t)t*U_ + u)*H_ + kq);
    const float* kp = key + t*H_ + kq;
    float s = 0.f;
#pragma unroll
    for (int k8 = 0; k8 < 16; ++k8) {
        const bf16x8 v = r8[k8];
#pragma unroll
        for (int j = 0; j < 8; ++j)
            s = fmaf(kp[k8*8 + j], bf2f((ushort)v[j]), s);
    }
    s += __shfl_xor(s, 1);
    s += __shfl_xor(s, 2);
    if ((tid & 3) == 0)
        alog[t*U_ + u] = attn_mask[t*U_ + u] ? s : -1e9f;
}

// B: softmax -> weights. grid T, 512 threads.
__global__ __launch_bounds__(512) void attn_softmax_kernel(
    const float* __restrict__ alog, float* __restrict__ aw)
{
    __shared__ float red[8];
    const int t = blockIdx.x, tid = threadIdx.x;
    const float v0 = alog[t*U_ + tid], v1 = alog[t*U_ + tid + 512];
    const float m = block_reduce_max<512>(fmaxf(v0, v1), red);
    const float e0 = __expf(v0 - m), e1 = __expf(v1 - m);
    const float s = block_reduce_sum<512>(e0 + e1, red);
    const float inv = 1.f / s;
    aw[t*U_ + tid] = e0 * inv;
    aw[t*U_ + tid + 512] = e1 * inv;
}

// C: weighted sum partials. grid (8, T), 512 threads = 8 u-slices x 64 h-octets.
__global__ __launch_bounds__(512) void attn_wsum_kernel(
    const ushort* __restrict__ db, const float* __restrict__ aw,
    float* __restrict__ part)
{
    __shared__ float sred[8][64][8];   // 16 KB
    const int t = blockIdx.y, u0 = blockIdx.x * 128;
    const int usub = threadIdx.x >> 6;   // 0..7
    const int h8   = threadIdx.x & 63;   // 0..63

    float a[8] = {};
    for (int uu = 0; uu < 16; ++uu) {
        const int u = u0 + usub*16 + uu;
        const float w = aw[t*U_ + u];
        const bf16x8 v = *(const bf16x8*)(db + ((size_t)t*U_ + u)*H_ + h8*8);
#pragma unroll
        for (int j = 0; j < 8; ++j) a[j] = fmaf(w, bf2f((ushort)v[j]), a[j]);
    }
#pragma unroll
    for (int j = 0; j < 8; ++j) sred[usub][h8][j] = a[j];
    __syncthreads();

    const int h8r = threadIdx.x >> 3;    // 0..63
    const int cr  = threadIdx.x & 7;     // 0..7
    float s = 0.f;
#pragma unroll
    for (int us = 0; us < 8; ++us) s += sred[us][h8r][cr];
    part[((size_t)blockIdx.x*T_ + t)*H_ + h8r*8 + cr] = s;
}

// ---------------------------------------------------------------------------
// feature = finf + sum(part) -> bf16
// ---------------------------------------------------------------------------
__global__ __launch_bounds__(256) void featcvt_kernel(
    const float* __restrict__ finf, const float* __restrict__ part,
    ushort* __restrict__ featb)
{
    const int row = blockIdx.x;       // t*64+l
    const int t = row >> 6;
    const int h = threadIdx.x * 2;
    const float2 v = *(const float2*)(finf + (size_t)row*H_ + h);
    float ax = 0.f, ay = 0.f;
#pragma unroll
    for (int p = 0; p < 8; ++p) {
        const float2 a = *(const float2*)(part + ((size_t)p*T_ + t)*H_ + h);
        ax += a.x; ay += a.y;
    }
    ushort2 o; o.x = f2bf(v.x + ax); o.y = f2bf(v.y + ay);
    *(ushort2*)(featb + (size_t)row*H_ + h) = o;
}

// ---------------------------------------------------------------------------
// ff = tanh(featb @ Wb^T + bb) -> bf16.  M=1024, N=512, K=512. Swizzled LDS.
// ---------------------------------------------------------------------------
__global__ __launch_bounds__(256) void ffgemm_kernel(
    const ushort* __restrict__ featb, const ushort* __restrict__ Wbb,
    const float* __restrict__ bb, ushort* __restrict__ ffb)
{
    __shared__ __align__(16) ushort As[128][BK];  // 16 KB
    __shared__ __align__(16) ushort Bs[64][BK];   // 8 KB

    const int tid = threadIdx.x;
    const int lane = tid & 63, wid = tid >> 6;
    const int wm = wid >> 1, wn = wid & 1;
    const int i0 = blockIdx.y * 128;
    const int j0 = blockIdx.x * 64;
    const int csw  = (((lane & 7) ^ (lane >> 3)) * 8);
    const int rsub = lane >> 3;

    f32x4 acc[4][2] = {};

    for (int k0 = 0; k0 < H_; k0 += BK) {
#pragma unroll
        for (int cc = wid; cc < 24; cc += 4) {
            if (cc < 16) {
                const ushort* g = featb + (size_t)(i0 + cc*8 + rsub)*H_ + k0 + csw;
                gload16(g, &As[0][0] + cc*512);
            } else {
                const int c = cc - 16;
                const ushort* g = Wbb + (size_t)(j0 + c*8 + rsub)*H_ + k0 + csw;
                gload16(g, &Bs[0][0] + c*512);
            }
        }
        __syncthreads();
#pragma unroll
        for (int s = 0; s < 2; ++s) {
            const int colr = (((s*4 + (lane>>4)) ^ (lane & 7)) * 8);
            bf16x8 af[4];
#pragma unroll
            for (int fm = 0; fm < 4; ++fm)
                af[fm] = *(const bf16x8*)&As[wm*64 + fm*16 + (lane&15)][colr];
#pragma unroll
            for (int fn = 0; fn < 2; ++fn) {
                const bf16x8 bv = *(const bf16x8*)&Bs[wn*32 + fn*16 + (lane&15)][colr];
#pragma unroll
                for (int fm = 0; fm < 4; ++fm)
                    acc[fm][fn] = __builtin_amdgcn_mfma_f32_16x16x32_bf16(
                        af[fm], bv, acc[fm][fn], 0, 0, 0);
            }
        }
        __syncthreads();
    }

#pragma unroll
    for (int fn = 0; fn < 2; ++fn) {
        const int j = j0 + wn*32 + fn*16 + (lane & 15);
        const float b = bb[j];
#pragma unroll
        for (int fm = 0; fm < 4; ++fm)
#pragma unroll
            for (int r = 0; r < 4; ++r) {
                const int i = i0 + wm*64 + fm*16 + (lane >> 4)*4 + r;
                ffb[(size_t)i*H_ + j] = f2bf(tanhf_(acc[fm][fn][r] + b));
            }
    }
}

// ---------------------------------------------------------------------------
// logits[t*64+l, n] = ff[t*64+l,:] . V[n,:].  Swizzled LDS.
// ---------------------------------------------------------------------------
__global__ __launch_bounds__(256) void logits_kernel(
    const ushort* __restrict__ ffb, const ushort* __restrict__ dbb,
    const ushort* __restrict__ Kembb, float* __restrict__ logits)
{
    __shared__ __align__(16) ushort As[64][BK];   // 8 KB
    __shared__ __align__(16) ushort Bs[64][BK];   // 8 KB

    const int tid = threadIdx.x;
    const int lane = tid & 63, wid = tid >> 6;
    const int t = blockIdx.y;
    const int bx = blockIdx.x;
    const bool kw = (bx == 16);
    const int csw  = (((lane & 7) ^ (lane >> 3)) * 8);
    const int rsub = lane >> 3;

    f32x4 acc[4] = {};

    for (int k0 = 0; k0 < H_; k0 += BK) {
#pragma unroll
        for (int cc = wid; cc < 16; cc += 4) {
            if (cc < 8) {
                const ushort* g = ffb + (size_t)(t*64 + cc*8 + rsub)*H_ + k0 + csw;
                gload16(g, &As[0][0] + cc*512);
            } else {
                const int rloc = (cc-8)*8 + rsub;
                const ushort* g = kw ? (Kembb + (size_t)rloc*H_ + k0 + csw)
                                     : (dbb + (size_t)(t*U_ + bx*64 + rloc)*H_ + k0 + csw);
                gload16(g, &Bs[0][0] + (cc-8)*512);
            }
        }
        __syncthreads();
#pragma unroll
        for (int s = 0; s < 2; ++s) {
            const int colr = (((s*4 + (lane>>4)) ^ (lane & 7)) * 8);
            const bf16x8 af = *(const bf16x8*)&As[wid*16 + (lane&15)][colr];
#pragma unroll
            for (int fn = 0; fn < 4; ++fn) {
                const bf16x8 bv = *(const bf16x8*)&Bs[fn*16 + (lane&15)][colr];
                acc[fn] = __builtin_amdgcn_mfma_f32_16x16x32_bf16(af, bv, acc[fn], 0, 0, 0);
            }
        }
        __syncthreads();
    }

    const int ncols = U_ + K_;
#pragma unroll
    for (int fn = 0; fn < 4; ++fn) {
        const int jg = (kw ? U_ : bx*64) + fn*16 + (lane & 15);
#pragma unroll
        for (int r = 0; r < 4; ++r) {
            const int i = t*64 + wid*16 + (lane >> 4)*4 + r;
            logits[(size_t)i*ncols + jg] = acc[fn][r];
        }
    }
}

// ---------------------------------------------------------------------------
// per-row log_softmax over 1088 logits
// ---------------------------------------------------------------------------
__global__ __launch_bounds__(256) void lsm_kernel(
    const float* __restrict__ logits, float* __restrict__ out)
{
    __shared__ float sl[U_ + K_];
    __shared__ float red[4];
    const int row = blockIdx.x;
    const int tid = threadIdx.x;
    const int ncols = U_ + K_;

    float m = -3.4e38f;
    for (int idx = tid; idx < ncols; idx += 256) {
        const float v = logits[(size_t)row*ncols + idx];
        sl[idx] = v;
        m = fmaxf(m, v);
    }
    __syncthreads();
    m = block_reduce_max<256>(m, red);

    float s = 0.f;
    for (int idx = tid; idx < ncols; idx += 256) s += __expf(sl[idx] - m);
    s = block_reduce_sum<256>(s, red);
    const float lse = m + __logf(s);

    for (int idx = tid; idx < ncols; idx += 256)
        out[(size_t)row*ncols + idx] = sl[idx] - lse;
}

// ---------------------------------------------------------------------------
extern "C" void kernel_launch(void* const* d_in, const int* in_sizes, int n_in,
                              void* d_out, int out_size, void* d_ws, size_t ws_size,
                              hipStream_t stream)
{
    const float* feat  = (const float*)d_in[0];
    const float* key   = (const float*)d_in[1];
    const float* finf  = (const float*)d_in[2];
    const float* Wih_f = (const float*)d_in[3];
    const float* Whh_f = (const float*)d_in[4];
    const float* bih_f = (const float*)d_in[5];
    const float* bhh_f = (const float*)d_in[6];
    const float* Wih_b = (const float*)d_in[7];
    const float* Whh_b = (const float*)d_in[8];
    const float* bih_b = (const float*)d_in[9];
    const float* bhh_b = (const float*)d_in[10];
    const float* Wb    = (const float*)d_in[11];
    const float* bb    = (const float*)d_in[12];
    const float* Kemb  = (const float*)d_in[13];
    const int* col_idx  = (const int*)d_in[14];
    const int* col_mask = (const int*)d_in[15];
    const int* tab_idx  = (const int*)d_in[16];
    const int* tab_mask = (const int*)d_in[17];
    const int* attn_mask= (const int*)d_in[18];
    float* out = (float*)d_out;

    char* p = (char*)d_ws;
    ushort* wbf  = (ushort*)p;  p += (size_t)(2*(S0_+S1_) + WB_ + KE_)*2;  // 2.95 MB
    ushort* x1b  = (ushort*)p;  p += (size_t)M_*H_*2;                      // 16.8 MB
    ushort* x2b  = (ushort*)p;  p += (size_t)M_*H_*2;
    ushort* f1b  = (ushort*)p;  p += (size_t)M_*Hh_*2;
    ushort* b1b  = (ushort*)p;  p += (size_t)M_*Hh_*2;
    ushort* dbb  = (ushort*)p;  p += (size_t)M_*H_*2;                      // 16.8 MB
    float*  alog = (float*)p;   p += (size_t)T_*U_*4;
    float*  aw   = (float*)p;   p += (size_t)T_*U_*4;
    float*  part = (float*)p;   p += (size_t)8*T_*H_*4;
    ushort* featb= (ushort*)p;  p += (size_t)T_*L_*H_*2;
    ushort* ffb  = (ushort*)p;  p += (size_t)T_*L_*H_*2;
    float*  lg   = (float*)p;   p += (size_t)T_*L_*(U_+K_)*4;              // 4.45 MB

    const ushort* Wihf_b = wbf;
    const ushort* Whhf_b = wbf + S0_;
    const ushort* Wihb_b = wbf + S0_ + S1_;
    const ushort* Whhb_b = wbf + 2*S0_ + S1_;
    const ushort* Wbb    = wbf + 2*(S0_ + S1_);
    const ushort* Kembb  = wbf + 2*(S0_ + S1_) + WB_;

    wcvt_kernel<<<(2*(S0_+S1_) + WB_ + KE_)/1024, 256, 0, stream>>>(
        Wih_f, Whh_f, Wih_b, Whh_b, Wb, Kemb, wbf);

    meanpool_kernel<<<dim3(U_, T_), 256, 0, stream>>>(
        feat, col_idx, col_mask, tab_idx, tab_mask, x1b, x2b);

    dim3 gg((M_/BM)*(Hh_/BNG), 1, 2);   // (1024, 1, 2), XCD-remapped in-kernel
    gru2_kernel<false><<<gg, 256, 0, stream>>>(
        x1b, x2b, nullptr, nullptr,
        Wihf_b, Wihb_b, Whhf_b, Whhb_b, bih_f, bih_b, bhh_f, bhh_b,
        f1b, b1b, nullptr, nullptr);
    gru2_kernel<true><<<gg, 256, 0, stream>>>(
        x2b, x1b, f1b, b1b,
        Wihf_b, Wihb_b, Whhf_b, Whhb_b, bih_f, bih_b, bhh_f, bhh_b,
        nullptr, nullptr, dbb, dbb + Hh_);

    attn_logits_kernel<<<dim3(16, T_), 256, 0, stream>>>(dbb, key, attn_mask, alog);
    attn_softmax_kernel<<<T_, 512, 0, stream>>>(alog, aw);
    attn_wsum_kernel<<<dim3(8, T_), 512, 0, stream>>>(dbb, aw, part);
    featcvt_kernel<<<T_*L_, 256, 0, stream>>>(finf, part, featb);
    ffgemm_kernel<<<dim3(H_/64, (T_*L_)/128), 256, 0, stream>>>(featb, Wbb, bb, ffb);
    logits_kernel<<<dim3(17, T_), 256, 0, stream>>>(ffb, dbb, Kembb, lg);
    lsm_kernel<<<T_*L_, 256, 0, stream>>>(lg, out);
}